// Round 3
// baseline (1010.172 us; speedup 1.0000x reference)
//
#include <hip/hip_runtime.h>

using u16    = unsigned short;
using bf16x8 = __attribute__((ext_vector_type(8))) short;
using f32x4  = __attribute__((ext_vector_type(4))) float;
using u16x4  = __attribute__((ext_vector_type(4))) u16;

#define NB   16
#define PP   2048
#define CC   64
#define KK   16
#define MROWS (NB*PP*KK)   /* 524288 */
#define NPTS  (NB*PP)      /* 32768  */

__device__ __forceinline__ float b2f(u16 u) { return __uint_as_float(((unsigned)u) << 16); }
__device__ __forceinline__ u16 f2b(float f) {
  unsigned u = __float_as_uint(f);
  return (u16)((u + 0x7fffu + ((u >> 16) & 1u)) >> 16);
}

// ---------------- prep: features (N,C,P) -> X (N,P,C) fp32 + bf16, r = sum x^2 ----------------
__global__ __launch_bounds__(256) void prep_k(const float* __restrict__ F,
                                              float* __restrict__ X,
                                              u16* __restrict__ Xb,
                                              float* __restrict__ r) {
  int gidx = blockIdx.x * 256 + threadIdx.x;      // 0..32767
  int n = gidx >> 11, p = gidx & 2047;
  const float* src = F + (size_t)n * CC * PP + p;
  float v[CC];
  float rr = 0.f;
  #pragma unroll
  for (int c = 0; c < CC; ++c) { v[c] = src[(size_t)c * PP]; rr += v[c] * v[c]; }
  float* dst = X + (size_t)gidx * CC;
  #pragma unroll
  for (int c = 0; c < CC; c += 4) {
    float4 w; w.x = v[c]; w.y = v[c+1]; w.z = v[c+2]; w.w = v[c+3];
    *(float4*)(dst + c) = w;
  }
  u16* db = Xb + (size_t)gidx * CC;
  #pragma unroll
  for (int c = 0; c < CC; c += 8) {
    bf16x8 w8;
    #pragma unroll
    for (int j = 0; j < 8; ++j) w8[j] = (short)f2b(v[c + j]);
    *(bf16x8*)(db + c) = w8;
  }
  r[gidx] = rr;
}

// ---------------- weight fp32 -> bf16 ----------------
__global__ __launch_bounds__(256) void cvtw_k(const float* __restrict__ w0, const float* __restrict__ w1,
                                              const float* __restrict__ w2, const float* __restrict__ wsb,
                                              u16* __restrict__ b0, u16* __restrict__ b1,
                                              u16* __restrict__ b2, u16* __restrict__ bs) {
  int i = blockIdx.x * 256 + threadIdx.x;         // 20480 total
  if (i < 8192)        b0[i]          = f2b(w0[i]);
  else if (i < 12288)  b1[i - 8192]   = f2b(w1[i - 8192]);
  else if (i < 16384)  b2[i - 12288]  = f2b(w2[i - 12288]);
  else if (i < 20480)  bs[i - 16384]  = f2b(wsb[i - 16384]);
}

// ---------------- branchless register top-16 insert (sorted ascending, stable) ----------------
__device__ __forceinline__ void ins16(float (&dl)[16], int (&il)[16], float d, int qi) {
  if (d < dl[15]) {
    #pragma unroll
    for (int s = 15; s >= 1; --s) {
      const bool sh_ = dl[s-1] > d;     // slot s-1 shifts down to s
      const bool me  = dl[s]   > d;     // d lands at s (first slot where dl[s] > d)
      dl[s] = sh_ ? dl[s-1] : (me ? d  : dl[s]);
      il[s] = sh_ ? il[s-1] : (me ? qi : il[s]);
    }
    if (dl[0] > d) { dl[0] = d; il[0] = qi; }
  }
}

// ---------------- fused KNN v3: 8x4 register-blocked GEMM + LDS D-tile + parallel top-16 ----------------
// WG(256) owns 64 p-rows x all 2048 q.  Per 128-q tile:
//   GEMM mapping: ph = t>>5 (8 p's), qh = t&31 (4 q's)  -> acc[8][4]
//   D-tile written into the Xq LDS buffer (dead after GEMM), XOR-swizzled 16B blocks
//   select mapping: row t&63, q-quarter t>>6, register top-16 (same order as v2 => same results)
__global__ __launch_bounds__(256) void knn_k(const float* __restrict__ X,
                                             const float* __restrict__ r,
                                             int* __restrict__ idx) {
  __shared__ float lds[12800];          // Xp [64][68] @ 0 ; Xq/D [64][132] @ 4352  (51.2 KB)
  float* Xp = lds;
  float* Xq = lds + 4352;

  const int n  = blockIdx.x >> 5;
  const int pb = (blockIdx.x & 31) * 64;
  const int t  = threadIdx.x;
  const float* Xn = X + (size_t)n * PP * CC;
  const float* rb = r + (size_t)n * PP;

  const int ph   = t >> 5;              // GEMM: 8 p-rows ph*8..ph*8+7
  const int qh   = t & 31;              // GEMM: 4 q-cols qh*4..qh*4+3
  const int prow = t & 63;              // select: own row
  const int qh2  = t >> 6;              // select: quarter of each tile
  const int u4   = (prow & 7) * 4;      // select-side swizzle key

  { // stage Xp transposed [c][p]
    const int pr = t & 63, ct = t >> 6;
    const float* src = Xn + (size_t)(pb + pr) * CC + ct * 16;
    #pragma unroll
    for (int j = 0; j < 16; j += 4) {
      float4 v = *(const float4*)(src + j);
      Xp[(ct*16 + j + 0) * 68 + pr] = v.x;
      Xp[(ct*16 + j + 1) * 68 + pr] = v.y;
      Xp[(ct*16 + j + 2) * 68 + pr] = v.z;
      Xp[(ct*16 + j + 3) * 68 + pr] = v.w;
    }
  }

  float dl[16]; int il[16];
  #pragma unroll
  for (int s = 0; s < 16; ++s) { dl[s] = 3.0e38f; il[s] = 0; }

  #pragma unroll 1
  for (int qb = 0; qb < PP; qb += 128) {
    __syncthreads();                    // previous select readers done (also covers Xp stage)
    { // stage Xq transposed [c][q]
      const int qr = t & 127, hf = t >> 7;
      const float* src = Xn + (size_t)(qb + qr) * CC + hf * 32;
      #pragma unroll
      for (int j = 0; j < 32; j += 4) {
        float4 v = *(const float4*)(src + j);
        Xq[(hf*32 + j + 0) * 132 + qr] = v.x;
        Xq[(hf*32 + j + 1) * 132 + qr] = v.y;
        Xq[(hf*32 + j + 2) * 132 + qr] = v.z;
        Xq[(hf*32 + j + 3) * 132 + qr] = v.w;
      }
    }
    __syncthreads();

    float acc[8][4];
    #pragma unroll
    for (int i = 0; i < 8; ++i)
      #pragma unroll
      for (int j = 0; j < 4; ++j) acc[i][j] = 0.f;

    #pragma unroll 4
    for (int c = 0; c < 64; ++c) {
      const float4 a0 = *(const float4*)&Xp[c*68 + ph*8];
      const float4 a1 = *(const float4*)&Xp[c*68 + ph*8 + 4];
      const float4 bq = *(const float4*)&Xq[c*132 + qh*4];
      float av[8] = {a0.x, a0.y, a0.z, a0.w, a1.x, a1.y, a1.z, a1.w};
      float bv[4] = {bq.x, bq.y, bq.z, bq.w};
      #pragma unroll
      for (int i = 0; i < 8; ++i)
        #pragma unroll
        for (int j = 0; j < 4; ++j)
          acc[i][j] = fmaf(av[i], bv[j], acc[i][j]);
    }
    __syncthreads();                    // all Xq reads done -> safe to overlay D

    { // write D tile (d = rq - 2*dot, self -> +big), swizzled: block qh stored at slot qh^(4*(p&7))
      const int qg0 = qb + qh*4;
      const float4 rv = *(const float4*)(rb + qg0);
      #pragma unroll
      for (int i = 0; i < 8; ++i) {
        const int p  = ph*8 + i;
        const int pg = pb + p;
        float d0 = rv.x - 2.f * acc[i][0]; if (qg0 + 0 == pg) d0 = 3.0e38f;
        float d1 = rv.y - 2.f * acc[i][1]; if (qg0 + 1 == pg) d1 = 3.0e38f;
        float d2 = rv.z - 2.f * acc[i][2]; if (qg0 + 2 == pg) d2 = 3.0e38f;
        float d3 = rv.w - 2.f * acc[i][3]; if (qg0 + 3 == pg) d3 = 3.0e38f;
        float4 dv; dv.x = d0; dv.y = d1; dv.z = d2; dv.w = d3;
        *(float4*)&Xq[(size_t)p * 132 + ((qh ^ (i*4)) * 4)] = dv;
      }
    }
    __syncthreads();

    // select: thread scans row `prow`, blocks b = qh2*8..+7 (ascending q)
    #pragma unroll 1
    for (int bb = 0; bb < 8; ++bb) {
      const int b = qh2*8 + bb;
      const float4 dv = *(const float4*)&Xq[(size_t)prow * 132 + ((b ^ u4) * 4)];
      const int qg = qb + b*4;
      const float m4 = fminf(fminf(dv.x, dv.y), fminf(dv.z, dv.w));
      if (m4 < dl[15]) {
        ins16(dl, il, dv.x, qg + 0);
        ins16(dl, il, dv.y, qg + 1);
        ins16(dl, il, dv.z, qg + 2);
        ins16(dl, il, dv.w, qg + 3);
      }
    }
  }

  // merge 4 partial top-16s per row (threads t, t+64, t+128, t+192) via Xq area
  __syncthreads();
  {
    float* mb = Xq;
    int*   mi = (int*)Xq + 4096;
    #pragma unroll
    for (int s = 0; s < 16; ++s) {
      mb[s * 256 + t] = dl[s];
      mi[s * 256 + t] = il[s];
    }
  }
  __syncthreads();
  if (t < 64) {
    const float* mb = Xq;
    const int*   mi = (const int*)Xq + 4096;
    #pragma unroll 1
    for (int j = 1; j < 4; ++j) {
      #pragma unroll 1
      for (int s = 0; s < 16; ++s) {
        const float d = mb[s * 256 + (t + 64 * j)];
        const int  qi = mi[s * 256 + (t + 64 * j)];
        ins16(dl, il, d, qi);
      }
    }
    #pragma unroll
    for (int s = 0; s < 16; ++s)
      idx[((size_t)n * PP + pb + t) * KK + s] = il[s];
  }
}

// ---------------- conv (MFMA bf16): y = A @ w^T + bias, fused per-WG BN partial stats ----------------
// GATHER: A rows built from Xb + idx ([fc, fc-f]); BNRELU: A = relu(in*s+t) from st.
template<int KIN, bool GATHER, bool BNRELU>
__global__ __launch_bounds__(256) void conv_k(const u16* __restrict__ in,
                                              const int* __restrict__ idxp,
                                              const u16* __restrict__ wb,
                                              const float* __restrict__ bias,
                                              const float* __restrict__ st,
                                              u16* __restrict__ yout,
                                              float* __restrict__ partials) {
  constexpr int NKB = KIN / 32;
  __shared__ float sred[4][4][32];
  const int t = threadIdx.x;
  const int wv = t >> 6, l = t & 63, hi = l >> 4, lo = l & 15;
  const int rbase = blockIdx.x * 256 + wv * 64;

  bf16x8 wf[4][NKB];
  #pragma unroll
  for (int ob = 0; ob < 4; ++ob)
    #pragma unroll
    for (int kb = 0; kb < NKB; ++kb)
      wf[ob][kb] = *(const bf16x8*)(wb + (size_t)(ob*16 + lo) * KIN + kb*32 + hi*8);

  int qv[4];
  if constexpr (GATHER) {
    #pragma unroll
    for (int rb = 0; rb < 4; ++rb) {
      const int g = (rbase + rb*16) >> 4;     // one point per 16-row block
      qv[rb] = idxp[g * KK + lo];
    }
  }

  f32x4 acc[4][4];
  #pragma unroll
  for (int a = 0; a < 4; ++a)
    #pragma unroll
    for (int b = 0; b < 4; ++b) { f32x4 z = {0.f, 0.f, 0.f, 0.f}; acc[a][b] = z; }

  #pragma unroll
  for (int kb = 0; kb < NKB; ++kb) {
    float sv[8], tv[8];
    if constexpr (BNRELU) {
      const int k0 = kb*32 + hi*8;
      *(float4*)&sv[0] = *(const float4*)(st + k0);
      *(float4*)&sv[4] = *(const float4*)(st + k0 + 4);
      *(float4*)&tv[0] = *(const float4*)(st + KIN + k0);
      *(float4*)&tv[4] = *(const float4*)(st + KIN + k0 + 4);
    }
    bf16x8 af[4];
    #pragma unroll
    for (int rb = 0; rb < 4; ++rb) {
      if constexpr (GATHER) {
        const int g  = (rbase + rb*16) >> 4;
        const int k0 = kb*32 + hi*8;
        const bf16x8 fc = *(const bf16x8*)(in + (size_t)g * CC + (k0 & 63));
        if (kb < 2) {
          af[rb] = fc;                                   // h[:, :64] = fc (broadcast rows)
        } else {
          const int nn = g >> 11;
          const bf16x8 fv = *(const bf16x8*)(in + (size_t)(nn * PP + qv[rb]) * CC + (k0 & 63));
          bf16x8 df;
          #pragma unroll
          for (int j = 0; j < 8; ++j)
            df[j] = (short)f2b(b2f((u16)fc[j]) - b2f((u16)fv[j]));
          af[rb] = df;
        }
      } else {
        const int row = rbase + rb*16 + lo;
        const bf16x8 rv = *(const bf16x8*)(in + (size_t)row * KIN + kb*32 + hi*8);
        if constexpr (BNRELU) {
          bf16x8 tr;
          #pragma unroll
          for (int j = 0; j < 8; ++j) {
            const float x = fmaxf(b2f((u16)rv[j]) * sv[j] + tv[j], 0.f);
            tr[j] = (short)f2b(x);
          }
          af[rb] = tr;
        } else {
          af[rb] = rv;
        }
      }
    }
    #pragma unroll
    for (int ob = 0; ob < 4; ++ob)
      #pragma unroll
      for (int rb = 0; rb < 4; ++rb)
        acc[rb][ob] = __builtin_amdgcn_mfma_f32_16x16x32_bf16(wf[ob][kb], af[rb], acc[rb][ob], 0, 0, 0);
  }

  // epilogue: D[row=(l>>4)*4+reg -> out ch][col=l&15 -> A row]; store + per-channel sum/sumsq
  float ssum[16], qsum[16];
  #pragma unroll
  for (int j = 0; j < 16; ++j) { ssum[j] = 0.f; qsum[j] = 0.f; }
  #pragma unroll
  for (int ob = 0; ob < 4; ++ob) {
    const int o0 = ob*16 + hi*4;
    const float4 bv = *(const float4*)(bias + o0);
    #pragma unroll
    for (int rb = 0; rb < 4; ++rb) {
      const int row = rbase + rb*16 + lo;
      const float v0 = acc[rb][ob][0] + bv.x;
      const float v1 = acc[rb][ob][1] + bv.y;
      const float v2 = acc[rb][ob][2] + bv.z;
      const float v3 = acc[rb][ob][3] + bv.w;
      u16x4 pk; pk[0] = f2b(v0); pk[1] = f2b(v1); pk[2] = f2b(v2); pk[3] = f2b(v3);
      *(u16x4*)(yout + (size_t)row * CC + o0) = pk;
      ssum[ob*4+0] += v0; qsum[ob*4+0] += v0*v0;
      ssum[ob*4+1] += v1; qsum[ob*4+1] += v1*v1;
      ssum[ob*4+2] += v2; qsum[ob*4+2] += v2*v2;
      ssum[ob*4+3] += v3; qsum[ob*4+3] += v3*v3;
    }
  }
  // reduce across the 16 lanes (lo) sharing this hi-group
  #pragma unroll
  for (int m = 1; m < 16; m <<= 1) {
    #pragma unroll
    for (int j = 0; j < 16; ++j) {
      ssum[j] += __shfl_xor(ssum[j], m, 64);
      qsum[j] += __shfl_xor(qsum[j], m, 64);
    }
  }
  if (lo == 0) {
    #pragma unroll
    for (int j = 0; j < 16; ++j) {
      sred[wv][hi][j*2]   = ssum[j];
      sred[wv][hi][j*2+1] = qsum[j];
    }
  }
  __syncthreads();
  if (t < 128) {
    const int c = t & 63, half = t >> 6;
    const int slot = ((c >> 4) * 4 + (c & 3)) * 2 + half;   // ob*4+e
    const int h2 = (c >> 2) & 3;
    const float v = sred[0][h2][slot] + sred[1][h2][slot] + sred[2][h2][slot] + sred[3][h2][slot];
    partials[(size_t)blockIdx.x * 128 + half * 64 + c] = v;
  }
}

// ---------------- reduce per-WG partials -> fused BN scale/bias ----------------
__global__ __launch_bounds__(256) void red_k(const float* __restrict__ partials,
                                             const float* __restrict__ g,
                                             const float* __restrict__ be,
                                             float* __restrict__ st, float invM, int nwg) {
  __shared__ float buf[4][64][2];
  const int t = threadIdx.x, c = t & 63, sl = t >> 6;
  float s = 0.f, q = 0.f;
  for (int w = sl; w < nwg; w += 4) {
    s += partials[(size_t)w * 128 + c];
    q += partials[(size_t)w * 128 + 64 + c];
  }
  buf[sl][c][0] = s; buf[sl][c][1] = q;
  __syncthreads();
  if (t < 64) {
    const float S = buf[0][t][0] + buf[1][t][0] + buf[2][t][0] + buf[3][t][0];
    const float Q = buf[0][t][1] + buf[1][t][1] + buf[2][t][1] + buf[3][t][1];
    const float m = S * invM;
    const float v = fmaxf(Q * invM - m * m, 0.f);
    const float sc = g[t] * rsqrtf(v + 1e-5f);
    st[t] = sc;
    st[64 + t] = be[t] - m * sc;
  }
}

// ---------------- final: bn2+relu, mean over K, + bn(shortcut), relu, (N,C,P) store ----------------
__global__ __launch_bounds__(256) void final_k(const u16* __restrict__ y2,
                                               const u16* __restrict__ ysc,
                                               const float* __restrict__ st2,
                                               const float* __restrict__ stS,
                                               float* __restrict__ out) {
  __shared__ float ot[64][68];
  const int b = blockIdx.x, t = threadIdx.x;
  const int n = b >> 5, p0 = (b & 31) * 64;
  const int phh = t >> 2, jh = t & 3, c0 = jh * 16;
  const int g = n * PP + p0 + phh;
  float acc[16];
  #pragma unroll
  for (int i = 0; i < 16; ++i) acc[i] = 0.f;
  float sv[16], tv[16];
  #pragma unroll
  for (int i = 0; i < 16; ++i) { sv[i] = st2[c0 + i]; tv[i] = st2[64 + c0 + i]; }
  for (int k = 0; k < KK; ++k) {
    const u16* rp = y2 + ((size_t)g * KK + k) * CC + c0;
    const bf16x8 v0 = *(const bf16x8*)rp;
    const bf16x8 v1 = *(const bf16x8*)(rp + 8);
    #pragma unroll
    for (int j = 0; j < 8; ++j) {
      acc[j]     += fmaxf(b2f((u16)v0[j]) * sv[j]     + tv[j],     0.f);
      acc[8 + j] += fmaxf(b2f((u16)v1[j]) * sv[8 + j] + tv[8 + j], 0.f);
    }
  }
  const u16* sp = ysc + (size_t)g * CC + c0;
  const bf16x8 s0 = *(const bf16x8*)sp;
  const bf16x8 s1 = *(const bf16x8*)(sp + 8);
  #pragma unroll
  for (int i = 0; i < 16; ++i) {
    const float scx = b2f((u16)(i < 8 ? s0[i] : s1[i - 8])) * stS[c0 + i] + stS[64 + c0 + i];
    ot[c0 + i][phh] = fmaxf(acc[i] * (1.f / 16.f) + scx, 0.f);
  }
  __syncthreads();
  const int c = t >> 2, pc = t & 3;
  const float* src = &ot[c][pc * 16];
  float* dst = out + (size_t)n * CC * PP + (size_t)c * PP + p0 + pc * 16;
  #pragma unroll
  for (int j = 0; j < 16; j += 4) *(float4*)(dst + j) = *(const float4*)(src + j);
}

// ---------------- host ----------------
extern "C" void kernel_launch(void* const* d_in, const int* in_sizes, int n_in,
                              void* d_out, int out_size, void* d_ws, size_t ws_size,
                              hipStream_t stream) {
  (void)in_sizes; (void)n_in; (void)out_size; (void)ws_size;
  const float* F   = (const float*)d_in[0];
  const float* w0  = (const float*)d_in[1];
  const float* b0  = (const float*)d_in[2];
  const float* g0  = (const float*)d_in[3];
  const float* be0 = (const float*)d_in[4];
  const float* w1  = (const float*)d_in[5];
  const float* b1  = (const float*)d_in[6];
  const float* g1  = (const float*)d_in[7];
  const float* be1 = (const float*)d_in[8];
  const float* w2  = (const float*)d_in[9];
  const float* b2  = (const float*)d_in[10];
  const float* g2  = (const float*)d_in[11];
  const float* be2 = (const float*)d_in[12];
  const float* wS  = (const float*)d_in[13];
  const float* bS  = (const float*)d_in[14];
  const float* gS  = (const float*)d_in[15];
  const float* beS = (const float*)d_in[16];

  char* ws = (char*)d_ws;
  size_t off = 0;
  auto carve = [&](size_t bytes) -> void* {
    void* p = ws + off;
    off += (bytes + 255) & ~(size_t)255;
    return p;
  };
  float* X        = (float*)carve((size_t)NPTS * CC * 4);       // 8.4 MB
  u16*   Xb       = (u16*)  carve((size_t)NPTS * CC * 2);       // 4.2 MB
  float* rr       = (float*)carve((size_t)NPTS * 4);            // 128 KB
  int*   idx      = (int*)  carve((size_t)NPTS * KK * 4);       // 2 MB
  u16*   wb0      = (u16*)  carve(8192 * 2);
  u16*   wb1      = (u16*)  carve(4096 * 2);
  u16*   wb2      = (u16*)  carve(4096 * 2);
  u16*   wbs      = (u16*)  carve(4096 * 2);
  u16*   y        = (u16*)  carve((size_t)MROWS * CC * 2);      // 67 MB
  u16*   ysc      = (u16*)  carve((size_t)NPTS * CC * 2);       // 4.2 MB
  float* partials = (float*)carve((size_t)2048 * 128 * 4);      // 1 MB
  float* st0      = (float*)carve(128 * 4);
  float* st1      = (float*)carve(128 * 4);
  float* st2      = (float*)carve(128 * 4);
  float* stS      = (float*)carve(128 * 4);

  prep_k<<<NPTS / 256, 256, 0, stream>>>(F, X, Xb, rr);
  cvtw_k<<<80, 256, 0, stream>>>(w0, w1, w2, wS, wb0, wb1, wb2, wbs);
  knn_k<<<NB * (PP / 64), 256, 0, stream>>>(X, rr, idx);

  conv_k<128, true,  false><<<MROWS / 256, 256, 0, stream>>>(Xb, idx, wb0, b0, nullptr, y, partials);
  red_k<<<1, 256, 0, stream>>>(partials, g0, be0, st0, 1.f / (float)MROWS, MROWS / 256);

  conv_k<64, false, true><<<MROWS / 256, 256, 0, stream>>>(y, nullptr, wb1, b1, st0, y, partials);
  red_k<<<1, 256, 0, stream>>>(partials, g1, be1, st1, 1.f / (float)MROWS, MROWS / 256);

  conv_k<64, false, true><<<MROWS / 256, 256, 0, stream>>>(y, nullptr, wb2, b2, st1, y, partials);
  red_k<<<1, 256, 0, stream>>>(partials, g2, be2, st2, 1.f / (float)MROWS, MROWS / 256);

  conv_k<64, false, false><<<NPTS / 256, 256, 0, stream>>>(Xb, nullptr, wbs, bS, nullptr, ysc, partials);
  red_k<<<1, 256, 0, stream>>>(partials, gS, beS, stS, 1.f / (float)NPTS, NPTS / 256);

  final_k<<<NB * (PP / 64), 256, 0, stream>>>(y, ysc, st2, stS, (float*)d_out);
}

// Round 4
// 429.282 us; speedup vs baseline: 2.3532x; 2.3532x over previous
//
#include <hip/hip_runtime.h>

using u16    = unsigned short;
using u64    = unsigned long long;
using bf16x8 = __attribute__((ext_vector_type(8))) short;
using f32x4  = __attribute__((ext_vector_type(4))) float;
using u16x4  = __attribute__((ext_vector_type(4))) u16;

#define NB   16
#define PP   2048
#define CC   64
#define KK   16
#define MROWS (NB*PP*KK)   /* 524288 */
#define NPTS  (NB*PP)      /* 32768  */

__device__ __forceinline__ float b2f(u16 u) { return __uint_as_float(((unsigned)u) << 16); }
__device__ __forceinline__ u16 f2b(float f) {
  unsigned u = __float_as_uint(f);
  return (u16)((u + 0x7fffu + ((u >> 16) & 1u)) >> 16);
}

// order-preserving (d, qi) -> u64 key: smaller key == smaller d, tie -> smaller qi
__device__ __forceinline__ u64 dkey(float d, int qi) {
  unsigned u = __float_as_uint(d);
  u = u ^ (((unsigned)((int)u >> 31)) | 0x80000000u);
  return ((u64)u << 32) | (unsigned)qi;
}

template<bool UP>
__device__ __forceinline__ void ce(u64 &a, u64 &b) {
  const bool lt = a < b;
  const u64 lo = lt ? a : b;
  const u64 hi = lt ? b : a;
  if (UP) { a = lo; b = hi; } else { a = hi; b = lo; }
}

// full bitonic sort, ascending
__device__ __forceinline__ void sort16(u64 (&v)[16]) {
  #pragma unroll
  for (int k = 2; k <= 16; k <<= 1) {
    #pragma unroll
    for (int j = k >> 1; j > 0; j >>= 1) {
      #pragma unroll
      for (int i = 0; i < 16; ++i) {
        const int l = i ^ j;
        if (l > i) {
          if ((i & k) == 0) ce<true>(v[i], v[l]);
          else              ce<false>(v[i], v[l]);
        }
      }
    }
  }
}

// dl (sorted asc) <- lowest 16 of union(dl, nb), nb sorted asc; result sorted asc
__device__ __forceinline__ void merge16(u64 (&dl)[16], const u64 (&nb)[16]) {
  u64 t[16];
  #pragma unroll
  for (int s = 0; s < 16; ++s) {
    const u64 a = dl[s], b = nb[15 - s];
    t[s] = a < b ? a : b;                 // bitonic sequence of the 16 smallest
  }
  #pragma unroll
  for (int j = 8; j > 0; j >>= 1) {
    #pragma unroll
    for (int i = 0; i < 16; ++i) {
      const int l = i ^ j;
      if (l > i) ce<true>(t[i], t[l]);
    }
  }
  #pragma unroll
  for (int s = 0; s < 16; ++s) dl[s] = t[s];
}

// ---------------- prep: features (N,C,P) -> X (N,P,C) fp32 + bf16, r = sum x^2 ----------------
__global__ __launch_bounds__(256) void prep_k(const float* __restrict__ F,
                                              float* __restrict__ X,
                                              u16* __restrict__ Xb,
                                              float* __restrict__ r) {
  int gidx = blockIdx.x * 256 + threadIdx.x;      // 0..32767
  int n = gidx >> 11, p = gidx & 2047;
  const float* src = F + (size_t)n * CC * PP + p;
  float v[CC];
  float rr = 0.f;
  #pragma unroll
  for (int c = 0; c < CC; ++c) { v[c] = src[(size_t)c * PP]; rr += v[c] * v[c]; }
  float* dst = X + (size_t)gidx * CC;
  #pragma unroll
  for (int c = 0; c < CC; c += 4) {
    float4 w; w.x = v[c]; w.y = v[c+1]; w.z = v[c+2]; w.w = v[c+3];
    *(float4*)(dst + c) = w;
  }
  u16* db = Xb + (size_t)gidx * CC;
  #pragma unroll
  for (int c = 0; c < CC; c += 8) {
    bf16x8 w8;
    #pragma unroll
    for (int j = 0; j < 8; ++j) w8[j] = (short)f2b(v[c + j]);
    *(bf16x8*)(db + c) = w8;
  }
  r[gidx] = rr;
}

// ---------------- weight fp32 -> bf16 ----------------
__global__ __launch_bounds__(256) void cvtw_k(const float* __restrict__ w0, const float* __restrict__ w1,
                                              const float* __restrict__ w2, const float* __restrict__ wsb,
                                              u16* __restrict__ b0, u16* __restrict__ b1,
                                              u16* __restrict__ b2, u16* __restrict__ bs) {
  int i = blockIdx.x * 256 + threadIdx.x;         // 20480 total
  if (i < 8192)        b0[i]          = f2b(w0[i]);
  else if (i < 12288)  b1[i - 8192]   = f2b(w1[i - 8192]);
  else if (i < 16384)  b2[i - 12288]  = f2b(w2[i - 12288]);
  else if (i < 20480)  bs[i - 16384]  = f2b(wsb[i - 16384]);
}

// ---------------- fused KNN v4: 8x4 register GEMM + LDS D-tile + batch-bitonic top-16 ----------------
// WG(256) owns 64 p-rows x all 2048 q.  Per 128-q tile:
//   GEMM mapping: ph = t>>5 (8 p's), qh = t&31 (4 q's)  -> acc[8][4]  (FMA order == prior rounds)
//   D-tile overlays Xq LDS (dead after GEMM), XOR-swizzled 16B blocks (0 conflicts)
//   select mapping: row t&63, quarter t>>6: two 16-candidate batches -> sort16 + merge16 (branchless)
__global__ __launch_bounds__(256, 3) void knn_k(const float* __restrict__ X,
                                                const float* __restrict__ r,
                                                int* __restrict__ idx) {
  __shared__ float lds[12800];          // Xp [64][68] @ 0 ; Xq/D [64][132] @ 4352  (51.2 KB)
  float* Xp = lds;
  float* Xq = lds + 4352;

  const int n  = blockIdx.x >> 5;
  const int pb = (blockIdx.x & 31) * 64;
  const int t  = threadIdx.x;
  const float* Xn = X + (size_t)n * PP * CC;
  const float* rb = r + (size_t)n * PP;

  const int ph   = t >> 5;              // GEMM: 8 p-rows ph*8..ph*8+7
  const int qh   = t & 31;              // GEMM: 4 q-cols qh*4..qh*4+3
  const int prow = t & 63;              // select: own row
  const int qh2  = t >> 6;              // select: quarter of each tile
  const int u4   = (prow & 7) * 4;      // select-side swizzle key

  { // stage Xp transposed [c][p]
    const int pr = t & 63, ct = t >> 6;
    const float* src = Xn + (size_t)(pb + pr) * CC + ct * 16;
    #pragma unroll
    for (int j = 0; j < 16; j += 4) {
      float4 v = *(const float4*)(src + j);
      Xp[(ct*16 + j + 0) * 68 + pr] = v.x;
      Xp[(ct*16 + j + 1) * 68 + pr] = v.y;
      Xp[(ct*16 + j + 2) * 68 + pr] = v.z;
      Xp[(ct*16 + j + 3) * 68 + pr] = v.w;
    }
  }

  u64 dl[16];
  #pragma unroll
  for (int s = 0; s < 16; ++s) dl[s] = ~0ULL;

  #pragma unroll 1
  for (int qb = 0; qb < PP; qb += 128) {
    __syncthreads();                    // previous select readers done (also covers Xp stage)
    { // stage Xq transposed [c][q]
      const int qr = t & 127, hf = t >> 7;
      const float* src = Xn + (size_t)(qb + qr) * CC + hf * 32;
      #pragma unroll
      for (int j = 0; j < 32; j += 4) {
        float4 v = *(const float4*)(src + j);
        Xq[(hf*32 + j + 0) * 132 + qr] = v.x;
        Xq[(hf*32 + j + 1) * 132 + qr] = v.y;
        Xq[(hf*32 + j + 2) * 132 + qr] = v.z;
        Xq[(hf*32 + j + 3) * 132 + qr] = v.w;
      }
    }
    __syncthreads();

    float acc[8][4];
    #pragma unroll
    for (int i = 0; i < 8; ++i)
      #pragma unroll
      for (int j = 0; j < 4; ++j) acc[i][j] = 0.f;

    #pragma unroll 4
    for (int c = 0; c < 64; ++c) {
      const float4 a0 = *(const float4*)&Xp[c*68 + ph*8];
      const float4 a1 = *(const float4*)&Xp[c*68 + ph*8 + 4];
      const float4 bq = *(const float4*)&Xq[c*132 + qh*4];
      float av[8] = {a0.x, a0.y, a0.z, a0.w, a1.x, a1.y, a1.z, a1.w};
      float bv[4] = {bq.x, bq.y, bq.z, bq.w};
      #pragma unroll
      for (int i = 0; i < 8; ++i)
        #pragma unroll
        for (int j = 0; j < 4; ++j)
          acc[i][j] = fmaf(av[i], bv[j], acc[i][j]);
    }
    __syncthreads();                    // all Xq reads done -> safe to overlay D

    { // write D tile (d = rq - 2*dot, self -> +big), block qh stored at slot qh^((p&7)*4)
      const int qg0 = qb + qh*4;
      const float4 rv = *(const float4*)(rb + qg0);
      #pragma unroll
      for (int i = 0; i < 8; ++i) {
        const int p  = ph*8 + i;
        const int pg = pb + p;
        float d0 = rv.x - 2.f * acc[i][0]; if (qg0 + 0 == pg) d0 = 3.0e38f;
        float d1 = rv.y - 2.f * acc[i][1]; if (qg0 + 1 == pg) d1 = 3.0e38f;
        float d2 = rv.z - 2.f * acc[i][2]; if (qg0 + 2 == pg) d2 = 3.0e38f;
        float d3 = rv.w - 2.f * acc[i][3]; if (qg0 + 3 == pg) d3 = 3.0e38f;
        float4 dv; dv.x = d0; dv.y = d1; dv.z = d2; dv.w = d3;
        *(float4*)&Xq[(size_t)p * 132 + ((qh ^ (i*4)) * 4)] = dv;
      }
    }
    __syncthreads();

    // select: thread scans row `prow`, blocks b = qh2*8..+7, as two 16-candidate batches
    #pragma unroll
    for (int half = 0; half < 2; ++half) {
      u64 nb[16];
      #pragma unroll
      for (int bi = 0; bi < 4; ++bi) {
        const int b = qh2*8 + half*4 + bi;
        const float4 dv = *(const float4*)&Xq[(size_t)prow * 132 + ((b ^ u4) * 4)];
        const int qg = qb + b*4;
        nb[bi*4+0] = dkey(dv.x, qg+0);
        nb[bi*4+1] = dkey(dv.y, qg+1);
        nb[bi*4+2] = dkey(dv.z, qg+2);
        nb[bi*4+3] = dkey(dv.w, qg+3);
      }
      sort16(nb);
      merge16(dl, nb);
    }
  }

  // merge 4 partial sorted lists per row (threads t, t+64, t+128, t+192) via Xq area (u64)
  __syncthreads();
  {
    u64* mb = (u64*)Xq;
    #pragma unroll
    for (int s = 0; s < 16; ++s) mb[s * 256 + t] = dl[s];
  }
  __syncthreads();
  if (t < 64) {
    const u64* mb = (const u64*)Xq;
    #pragma unroll 1
    for (int j = 1; j < 4; ++j) {
      u64 nb[16];
      #pragma unroll
      for (int s = 0; s < 16; ++s) nb[s] = mb[s * 256 + (t + 64 * j)];
      merge16(dl, nb);
    }
    #pragma unroll
    for (int s = 0; s < 16; ++s)
      idx[((size_t)n * PP + pb + t) * KK + s] = (int)(dl[s] & 0xFFFFFFFFu);
  }
}

// ---------------- conv (MFMA bf16): y = A @ w^T + bias, fused per-WG BN partial stats ----------------
template<int KIN, bool GATHER, bool BNRELU>
__global__ __launch_bounds__(256) void conv_k(const u16* __restrict__ in,
                                              const int* __restrict__ idxp,
                                              const u16* __restrict__ wb,
                                              const float* __restrict__ bias,
                                              const float* __restrict__ st,
                                              u16* __restrict__ yout,
                                              float* __restrict__ partials) {
  constexpr int NKB = KIN / 32;
  __shared__ float sred[4][4][32];
  const int t = threadIdx.x;
  const int wv = t >> 6, l = t & 63, hi = l >> 4, lo = l & 15;
  const int rbase = blockIdx.x * 256 + wv * 64;

  bf16x8 wf[4][NKB];
  #pragma unroll
  for (int ob = 0; ob < 4; ++ob)
    #pragma unroll
    for (int kb = 0; kb < NKB; ++kb)
      wf[ob][kb] = *(const bf16x8*)(wb + (size_t)(ob*16 + lo) * KIN + kb*32 + hi*8);

  int qv[4];
  if constexpr (GATHER) {
    #pragma unroll
    for (int rb = 0; rb < 4; ++rb) {
      const int g = (rbase + rb*16) >> 4;     // one point per 16-row block
      qv[rb] = idxp[g * KK + lo];
    }
  }

  f32x4 acc[4][4];
  #pragma unroll
  for (int a = 0; a < 4; ++a)
    #pragma unroll
    for (int b = 0; b < 4; ++b) { f32x4 z = {0.f, 0.f, 0.f, 0.f}; acc[a][b] = z; }

  #pragma unroll
  for (int kb = 0; kb < NKB; ++kb) {
    float sv[8], tv[8];
    if constexpr (BNRELU) {
      const int k0 = kb*32 + hi*8;
      *(float4*)&sv[0] = *(const float4*)(st + k0);
      *(float4*)&sv[4] = *(const float4*)(st + k0 + 4);
      *(float4*)&tv[0] = *(const float4*)(st + KIN + k0);
      *(float4*)&tv[4] = *(const float4*)(st + KIN + k0 + 4);
    }
    bf16x8 af[4];
    #pragma unroll
    for (int rb = 0; rb < 4; ++rb) {
      if constexpr (GATHER) {
        const int g  = (rbase + rb*16) >> 4;
        const int k0 = kb*32 + hi*8;
        const bf16x8 fc = *(const bf16x8*)(in + (size_t)g * CC + (k0 & 63));
        if (kb < 2) {
          af[rb] = fc;                                   // h[:, :64] = fc (broadcast rows)
        } else {
          const int nn = g >> 11;
          const bf16x8 fv = *(const bf16x8*)(in + (size_t)(nn * PP + qv[rb]) * CC + (k0 & 63));
          bf16x8 df;
          #pragma unroll
          for (int j = 0; j < 8; ++j)
            df[j] = (short)f2b(b2f((u16)fc[j]) - b2f((u16)fv[j]));
          af[rb] = df;
        }
      } else {
        const int row = rbase + rb*16 + lo;
        const bf16x8 rv = *(const bf16x8*)(in + (size_t)row * KIN + kb*32 + hi*8);
        if constexpr (BNRELU) {
          bf16x8 tr;
          #pragma unroll
          for (int j = 0; j < 8; ++j) {
            const float x = fmaxf(b2f((u16)rv[j]) * sv[j] + tv[j], 0.f);
            tr[j] = (short)f2b(x);
          }
          af[rb] = tr;
        } else {
          af[rb] = rv;
        }
      }
    }
    #pragma unroll
    for (int ob = 0; ob < 4; ++ob)
      #pragma unroll
      for (int rb = 0; rb < 4; ++rb)
        acc[rb][ob] = __builtin_amdgcn_mfma_f32_16x16x32_bf16(wf[ob][kb], af[rb], acc[rb][ob], 0, 0, 0);
  }

  // epilogue: D[row=(l>>4)*4+reg -> out ch][col=l&15 -> A row]; store + per-channel sum/sumsq
  float ssum[16], qsum[16];
  #pragma unroll
  for (int j = 0; j < 16; ++j) { ssum[j] = 0.f; qsum[j] = 0.f; }
  #pragma unroll
  for (int ob = 0; ob < 4; ++ob) {
    const int o0 = ob*16 + hi*4;
    const float4 bv = *(const float4*)(bias + o0);
    #pragma unroll
    for (int rb = 0; rb < 4; ++rb) {
      const int row = rbase + rb*16 + lo;
      const float v0 = acc[rb][ob][0] + bv.x;
      const float v1 = acc[rb][ob][1] + bv.y;
      const float v2 = acc[rb][ob][2] + bv.z;
      const float v3 = acc[rb][ob][3] + bv.w;
      u16x4 pk; pk[0] = f2b(v0); pk[1] = f2b(v1); pk[2] = f2b(v2); pk[3] = f2b(v3);
      *(u16x4*)(yout + (size_t)row * CC + o0) = pk;
      ssum[ob*4+0] += v0; qsum[ob*4+0] += v0*v0;
      ssum[ob*4+1] += v1; qsum[ob*4+1] += v1*v1;
      ssum[ob*4+2] += v2; qsum[ob*4+2] += v2*v2;
      ssum[ob*4+3] += v3; qsum[ob*4+3] += v3*v3;
    }
  }
  #pragma unroll
  for (int m = 1; m < 16; m <<= 1) {
    #pragma unroll
    for (int j = 0; j < 16; ++j) {
      ssum[j] += __shfl_xor(ssum[j], m, 64);
      qsum[j] += __shfl_xor(qsum[j], m, 64);
    }
  }
  if (lo == 0) {
    #pragma unroll
    for (int j = 0; j < 16; ++j) {
      sred[wv][hi][j*2]   = ssum[j];
      sred[wv][hi][j*2+1] = qsum[j];
    }
  }
  __syncthreads();
  if (t < 128) {
    const int c = t & 63, half = t >> 6;
    const int slot = ((c >> 4) * 4 + (c & 3)) * 2 + half;   // ob*4+e
    const int h2 = (c >> 2) & 3;
    const float v = sred[0][h2][slot] + sred[1][h2][slot] + sred[2][h2][slot] + sred[3][h2][slot];
    partials[(size_t)blockIdx.x * 128 + half * 64 + c] = v;
  }
}

// ---------------- stage-1 reduce: nwg partial rows -> 64 rows ----------------
__global__ __launch_bounds__(256) void red1_k(const float* __restrict__ partials,
                                              float* __restrict__ out, int nwg) {
  __shared__ float accs[2][128];
  const int t = threadIdx.x, e = t & 127, h = t >> 7;
  float s = 0.f;
  for (int w = blockIdx.x + h * 64; w < nwg; w += 128)
    s += partials[(size_t)w * 128 + e];
  accs[h][e] = s;
  __syncthreads();
  if (t < 128) out[(size_t)blockIdx.x * 128 + t] = accs[0][t] + accs[1][t];
}

// ---------------- stage-2: 64 rows -> fused BN scale/bias ----------------
__global__ __launch_bounds__(128) void red2_k(const float* __restrict__ p2,
                                              const float* __restrict__ g,
                                              const float* __restrict__ be,
                                              float* __restrict__ st, float invM) {
  __shared__ float sq[128];
  const int t = threadIdx.x;            // element t: [0,64)=sum, [64,128)=sumsq
  float s = 0.f;
  #pragma unroll 8
  for (int w = 0; w < 64; ++w) s += p2[w * 128 + t];
  sq[t] = s;
  __syncthreads();
  if (t < 64) {
    const float S = sq[t], Q = sq[64 + t];
    const float m = S * invM;
    const float v = fmaxf(Q * invM - m * m, 0.f);
    const float sc = g[t] * rsqrtf(v + 1e-5f);
    st[t] = sc;
    st[64 + t] = be[t] - m * sc;
  }
}

// ---------------- final: bn2+relu, mean over K, + bn(shortcut), relu, (N,C,P) store ----------------
__global__ __launch_bounds__(256) void final_k(const u16* __restrict__ y2,
                                               const u16* __restrict__ ysc,
                                               const float* __restrict__ st2,
                                               const float* __restrict__ stS,
                                               float* __restrict__ out) {
  __shared__ float ot[64][68];
  const int b = blockIdx.x, t = threadIdx.x;
  const int n = b >> 5, p0 = (b & 31) * 64;
  const int phh = t >> 2, jh = t & 3, c0 = jh * 16;
  const int g = n * PP + p0 + phh;
  float acc[16];
  #pragma unroll
  for (int i = 0; i < 16; ++i) acc[i] = 0.f;
  float sv[16], tv[16];
  #pragma unroll
  for (int i = 0; i < 16; ++i) { sv[i] = st2[c0 + i]; tv[i] = st2[64 + c0 + i]; }
  for (int k = 0; k < KK; ++k) {
    const u16* rp = y2 + ((size_t)g * KK + k) * CC + c0;
    const bf16x8 v0 = *(const bf16x8*)rp;
    const bf16x8 v1 = *(const bf16x8*)(rp + 8);
    #pragma unroll
    for (int j = 0; j < 8; ++j) {
      acc[j]     += fmaxf(b2f((u16)v0[j]) * sv[j]     + tv[j],     0.f);
      acc[8 + j] += fmaxf(b2f((u16)v1[j]) * sv[8 + j] + tv[8 + j], 0.f);
    }
  }
  const u16* sp = ysc + (size_t)g * CC + c0;
  const bf16x8 s0 = *(const bf16x8*)sp;
  const bf16x8 s1 = *(const bf16x8*)(sp + 8);
  #pragma unroll
  for (int i = 0; i < 16; ++i) {
    const float scx = b2f((u16)(i < 8 ? s0[i] : s1[i - 8])) * stS[c0 + i] + stS[64 + c0 + i];
    ot[c0 + i][phh] = fmaxf(acc[i] * (1.f / 16.f) + scx, 0.f);
  }
  __syncthreads();
  const int c = t >> 2, pc = t & 3;
  const float* src = &ot[c][pc * 16];
  float* dst = out + (size_t)n * CC * PP + (size_t)c * PP + p0 + pc * 16;
  #pragma unroll
  for (int j = 0; j < 16; j += 4) *(float4*)(dst + j) = *(const float4*)(src + j);
}

// ---------------- host ----------------
extern "C" void kernel_launch(void* const* d_in, const int* in_sizes, int n_in,
                              void* d_out, int out_size, void* d_ws, size_t ws_size,
                              hipStream_t stream) {
  (void)in_sizes; (void)n_in; (void)out_size; (void)ws_size;
  const float* F   = (const float*)d_in[0];
  const float* w0  = (const float*)d_in[1];
  const float* b0  = (const float*)d_in[2];
  const float* g0  = (const float*)d_in[3];
  const float* be0 = (const float*)d_in[4];
  const float* w1  = (const float*)d_in[5];
  const float* b1  = (const float*)d_in[6];
  const float* g1  = (const float*)d_in[7];
  const float* be1 = (const float*)d_in[8];
  const float* w2  = (const float*)d_in[9];
  const float* b2  = (const float*)d_in[10];
  const float* g2  = (const float*)d_in[11];
  const float* be2 = (const float*)d_in[12];
  const float* wS  = (const float*)d_in[13];
  const float* bS  = (const float*)d_in[14];
  const float* gS  = (const float*)d_in[15];
  const float* beS = (const float*)d_in[16];

  char* ws = (char*)d_ws;
  size_t off = 0;
  auto carve = [&](size_t bytes) -> void* {
    void* p = ws + off;
    off += (bytes + 255) & ~(size_t)255;
    return p;
  };
  float* X        = (float*)carve((size_t)NPTS * CC * 4);       // 8.4 MB
  u16*   Xb       = (u16*)  carve((size_t)NPTS * CC * 2);       // 4.2 MB
  float* rr       = (float*)carve((size_t)NPTS * 4);            // 128 KB
  int*   idx      = (int*)  carve((size_t)NPTS * KK * 4);       // 2 MB
  u16*   wb0      = (u16*)  carve(8192 * 2);
  u16*   wb1      = (u16*)  carve(4096 * 2);
  u16*   wb2      = (u16*)  carve(4096 * 2);
  u16*   wbs      = (u16*)  carve(4096 * 2);
  u16*   y        = (u16*)  carve((size_t)MROWS * CC * 2);      // 67 MB
  u16*   ysc      = (u16*)  carve((size_t)NPTS * CC * 2);       // 4.2 MB
  float* partials = (float*)carve((size_t)2048 * 128 * 4);      // 1 MB
  float* p2       = (float*)carve((size_t)64 * 128 * 4);        // 32 KB
  float* st0      = (float*)carve(128 * 4);
  float* st1      = (float*)carve(128 * 4);
  float* st2      = (float*)carve(128 * 4);
  float* stS      = (float*)carve(128 * 4);

  prep_k<<<NPTS / 256, 256, 0, stream>>>(F, X, Xb, rr);
  cvtw_k<<<80, 256, 0, stream>>>(w0, w1, w2, wS, wb0, wb1, wb2, wbs);
  knn_k<<<NB * (PP / 64), 256, 0, stream>>>(X, rr, idx);

  conv_k<128, true,  false><<<MROWS / 256, 256, 0, stream>>>(Xb, idx, wb0, b0, nullptr, y, partials);
  red1_k<<<64, 256, 0, stream>>>(partials, p2, MROWS / 256);
  red2_k<<<1, 128, 0, stream>>>(p2, g0, be0, st0, 1.f / (float)MROWS);

  conv_k<64, false, true><<<MROWS / 256, 256, 0, stream>>>(y, nullptr, wb1, b1, st0, y, partials);
  red1_k<<<64, 256, 0, stream>>>(partials, p2, MROWS / 256);
  red2_k<<<1, 128, 0, stream>>>(p2, g1, be1, st1, 1.f / (float)MROWS);

  conv_k<64, false, true><<<MROWS / 256, 256, 0, stream>>>(y, nullptr, wb2, b2, st1, y, partials);
  red1_k<<<64, 256, 0, stream>>>(partials, p2, MROWS / 256);
  red2_k<<<1, 128, 0, stream>>>(p2, g2, be2, st2, 1.f / (float)MROWS);

  conv_k<64, false, false><<<NPTS / 256, 256, 0, stream>>>(Xb, nullptr, wbs, bS, nullptr, ysc, partials);
  red1_k<<<64, 256, 0, stream>>>(partials, p2, NPTS / 256);
  red2_k<<<1, 128, 0, stream>>>(p2, gS, beS, stS, 1.f / (float)NPTS);

  final_k<<<NB * (PP / 64), 256, 0, stream>>>(y, ysc, st2, stS, (float*)d_out);
}

// Round 5
// 421.255 us; speedup vs baseline: 2.3980x; 1.0191x over previous
//
#include <hip/hip_runtime.h>

using u16    = unsigned short;
using u64    = unsigned long long;
using bf16x8 = __attribute__((ext_vector_type(8))) short;
using f32x4  = __attribute__((ext_vector_type(4))) float;
using u16x4  = __attribute__((ext_vector_type(4))) u16;

#define NB   16
#define PP   2048
#define CC   64
#define KK   16
#define MROWS (NB*PP*KK)   /* 524288 */
#define NPTS  (NB*PP)      /* 32768  */

__device__ __forceinline__ float b2f(u16 u) { return __uint_as_float(((unsigned)u) << 16); }
__device__ __forceinline__ u16 f2b(float f) {
  unsigned u = __float_as_uint(f);
  return (u16)((u + 0x7fffu + ((u >> 16) & 1u)) >> 16);
}

// order-preserving (d, qi) -> u64 key: smaller key == smaller d, tie -> smaller qi
__device__ __forceinline__ u64 dkey(float d, int qi) {
  unsigned u = __float_as_uint(d);
  u = u ^ (((unsigned)((int)u >> 31)) | 0x80000000u);
  return ((u64)u << 32) | (unsigned)qi;
}

template<bool UP>
__device__ __forceinline__ void ce(u64 &a, u64 &b) {
  const bool lt = a < b;
  const u64 lo = lt ? a : b;
  const u64 hi = lt ? b : a;
  if (UP) { a = lo; b = hi; } else { a = hi; b = lo; }
}

// full bitonic sort, ascending
__device__ __forceinline__ void sort16(u64 (&v)[16]) {
  #pragma unroll
  for (int k = 2; k <= 16; k <<= 1) {
    #pragma unroll
    for (int j = k >> 1; j > 0; j >>= 1) {
      #pragma unroll
      for (int i = 0; i < 16; ++i) {
        const int l = i ^ j;
        if (l > i) {
          if ((i & k) == 0) ce<true>(v[i], v[l]);
          else              ce<false>(v[i], v[l]);
        }
      }
    }
  }
}

// dl (sorted asc) <- lowest 16 of union(dl, nb), nb sorted asc; result sorted asc
__device__ __forceinline__ void merge16(u64 (&dl)[16], const u64 (&nb)[16]) {
  u64 t[16];
  #pragma unroll
  for (int s = 0; s < 16; ++s) {
    const u64 a = dl[s], b = nb[15 - s];
    t[s] = a < b ? a : b;                 // bitonic sequence of the 16 smallest
  }
  #pragma unroll
  for (int j = 8; j > 0; j >>= 1) {
    #pragma unroll
    for (int i = 0; i < 16; ++i) {
      const int l = i ^ j;
      if (l > i) ce<true>(t[i], t[l]);
    }
  }
  #pragma unroll
  for (int s = 0; s < 16; ++s) dl[s] = t[s];
}

// ---------------- prep: features (N,C,P) -> X (N,P,C) fp32 + bf16, r = sum x^2 ----------------
__global__ __launch_bounds__(256) void prep_k(const float* __restrict__ F,
                                              float* __restrict__ X,
                                              u16* __restrict__ Xb,
                                              float* __restrict__ r) {
  int gidx = blockIdx.x * 256 + threadIdx.x;      // 0..32767
  int n = gidx >> 11, p = gidx & 2047;
  const float* src = F + (size_t)n * CC * PP + p;
  float v[CC];
  float rr = 0.f;
  #pragma unroll
  for (int c = 0; c < CC; ++c) { v[c] = src[(size_t)c * PP]; rr += v[c] * v[c]; }
  float* dst = X + (size_t)gidx * CC;
  #pragma unroll
  for (int c = 0; c < CC; c += 4) {
    float4 w; w.x = v[c]; w.y = v[c+1]; w.z = v[c+2]; w.w = v[c+3];
    *(float4*)(dst + c) = w;
  }
  u16* db = Xb + (size_t)gidx * CC;
  #pragma unroll
  for (int c = 0; c < CC; c += 8) {
    bf16x8 w8;
    #pragma unroll
    for (int j = 0; j < 8; ++j) w8[j] = (short)f2b(v[c + j]);
    *(bf16x8*)(db + c) = w8;
  }
  r[gidx] = rr;
}

// ---------------- weight fp32 -> bf16 ----------------
__global__ __launch_bounds__(256) void cvtw_k(const float* __restrict__ w0, const float* __restrict__ w1,
                                              const float* __restrict__ w2, const float* __restrict__ wsb,
                                              u16* __restrict__ b0, u16* __restrict__ b1,
                                              u16* __restrict__ b2, u16* __restrict__ bs) {
  int i = blockIdx.x * 256 + threadIdx.x;         // 20480 total
  if (i < 8192)        b0[i]          = f2b(w0[i]);
  else if (i < 12288)  b1[i - 8192]   = f2b(w1[i - 8192]);
  else if (i < 16384)  b2[i - 12288]  = f2b(w2[i - 12288]);
  else if (i < 20480)  bs[i - 16384]  = f2b(wsb[i - 16384]);
}

// ---------------- fused KNN v5: WG=512 (8 waves), 4x4 register GEMM + LDS D-tile + bitonic top-16 ----
// WG owns 64 p-rows x all 2048 q.  Per 128-q tile:
//   GEMM: pg = t>>5 (4 rows pg*4..+3), qh = t&31 (4 cols qh*4..+3) -> acc[4][4]
//         per-(p,q) FMA chain over c ascending == prior rounds -> bitwise-identical distances
//   D-tile overlays Xq LDS (dead after GEMM), XOR-swizzled 16B blocks
//   select: row t&63, eighth t>>6 (== wave): one 16-candidate batch -> sort16 + merge16
__global__ __launch_bounds__(512, 4) void knn_k(const float* __restrict__ X,
                                                const float* __restrict__ r,
                                                int* __restrict__ idx) {
  __shared__ float lds[12800];          // Xp [64][68] @ 0 ; Xq/D [64][132] @ 4352  (51.2 KB)
  float* Xp = lds;
  float* Xq = lds + 4352;

  const int n  = blockIdx.x >> 5;
  const int pb = (blockIdx.x & 31) * 64;
  const int t  = threadIdx.x;
  const float* Xn = X + (size_t)n * PP * CC;
  const float* rb = r + (size_t)n * PP;

  const int qh   = t & 31;              // GEMM: 4 q-cols qh*4..+3
  const int pg   = t >> 5;              // GEMM: 4 p-rows pg*4..+3 (0..15)
  const int prow = t & 63;              // select: own row
  const int w8   = t >> 6;              // select: eighth (== wave index)
  const int u4   = (prow & 7) * 4;      // select-side swizzle key

  { // stage Xp transposed [c][p]: 512 threads, 8 channels each
    const int pr = t & 63, ct = t >> 6;
    const float* src = Xn + (size_t)(pb + pr) * CC + ct * 8;
    #pragma unroll
    for (int j = 0; j < 8; j += 4) {
      float4 v = *(const float4*)(src + j);
      Xp[(ct*8 + j + 0) * 68 + pr] = v.x;
      Xp[(ct*8 + j + 1) * 68 + pr] = v.y;
      Xp[(ct*8 + j + 2) * 68 + pr] = v.z;
      Xp[(ct*8 + j + 3) * 68 + pr] = v.w;
    }
  }

  u64 dl[16];
  #pragma unroll
  for (int s = 0; s < 16; ++s) dl[s] = ~0ULL;

  #pragma unroll 1
  for (int qb = 0; qb < PP; qb += 128) {
    __syncthreads();                    // previous select readers done (also covers Xp stage)
    { // stage Xq transposed [c][q]: 512 threads, 16 channels of one q-row each
      const int qr = t >> 2, ch = (t & 3) * 16;
      const float* src = Xn + (size_t)(qb + qr) * CC + ch;
      #pragma unroll
      for (int j = 0; j < 16; j += 4) {
        float4 v = *(const float4*)(src + j);
        Xq[(ch + j + 0) * 132 + qr] = v.x;
        Xq[(ch + j + 1) * 132 + qr] = v.y;
        Xq[(ch + j + 2) * 132 + qr] = v.z;
        Xq[(ch + j + 3) * 132 + qr] = v.w;
      }
    }
    __syncthreads();

    float acc[4][4];
    #pragma unroll
    for (int i = 0; i < 4; ++i)
      #pragma unroll
      for (int j = 0; j < 4; ++j) acc[i][j] = 0.f;

    #pragma unroll 4
    for (int c = 0; c < 64; ++c) {
      const float4 a = *(const float4*)&Xp[c*68 + pg*4];
      const float4 bq = *(const float4*)&Xq[c*132 + qh*4];
      float av[4] = {a.x, a.y, a.z, a.w};
      float bv[4] = {bq.x, bq.y, bq.z, bq.w};
      #pragma unroll
      for (int i = 0; i < 4; ++i)
        #pragma unroll
        for (int j = 0; j < 4; ++j)
          acc[i][j] = fmaf(av[i], bv[j], acc[i][j]);
    }
    __syncthreads();                    // all Xq reads done -> safe to overlay D

    { // write D tile (d = rq - 2*dot, self -> +big), block qh stored at slot qh^((p&7)*4)
      const int qg0 = qb + qh*4;
      const float4 rv = *(const float4*)(rb + qg0);
      #pragma unroll
      for (int i = 0; i < 4; ++i) {
        const int p  = pg*4 + i;
        const int pgl = pb + p;
        float d0 = rv.x - 2.f * acc[i][0]; if (qg0 + 0 == pgl) d0 = 3.0e38f;
        float d1 = rv.y - 2.f * acc[i][1]; if (qg0 + 1 == pgl) d1 = 3.0e38f;
        float d2 = rv.z - 2.f * acc[i][2]; if (qg0 + 2 == pgl) d2 = 3.0e38f;
        float d3 = rv.w - 2.f * acc[i][3]; if (qg0 + 3 == pgl) d3 = 3.0e38f;
        float4 dv; dv.x = d0; dv.y = d1; dv.z = d2; dv.w = d3;
        *(float4*)&Xq[(size_t)p * 132 + ((qh ^ ((p & 7) * 4)) * 4)] = dv;
      }
    }
    __syncthreads();

    // select: thread scans row `prow`, blocks b = w8*4..+3 -> one 16-candidate batch
    {
      u64 nb[16];
      #pragma unroll
      for (int bb = 0; bb < 4; ++bb) {
        const int b = w8*4 + bb;
        const float4 dv = *(const float4*)&Xq[(size_t)prow * 132 + ((b ^ u4) * 4)];
        const int qg = qb + b*4;
        nb[bb*4+0] = dkey(dv.x, qg+0);
        nb[bb*4+1] = dkey(dv.y, qg+1);
        nb[bb*4+2] = dkey(dv.z, qg+2);
        nb[bb*4+3] = dkey(dv.w, qg+3);
      }
      sort16(nb);
      merge16(dl, nb);
    }
  }

  // merge 8 partial sorted lists per row: pair-merge (t vs t+256), then 4-way via LDS
  __syncthreads();
  {
    u64* mb = (u64*)lds;                // 16*256 u64 = 32 KB
    if (t >= 256) {
      #pragma unroll
      for (int s = 0; s < 16; ++s) mb[s * 256 + (t - 256)] = dl[s];
    }
    __syncthreads();
    if (t < 256) {
      u64 nb[16];
      #pragma unroll
      for (int s = 0; s < 16; ++s) nb[s] = mb[s * 256 + t];
      merge16(dl, nb);
    }
    __syncthreads();
    if (t < 256) {
      #pragma unroll
      for (int s = 0; s < 16; ++s) mb[s * 256 + t] = dl[s];
    }
    __syncthreads();
    if (t < 64) {
      #pragma unroll 1
      for (int j = 1; j < 4; ++j) {
        u64 nb[16];
        #pragma unroll
        for (int s = 0; s < 16; ++s) nb[s] = mb[s * 256 + (t + 64 * j)];
        merge16(dl, nb);
      }
      #pragma unroll
      for (int s = 0; s < 16; ++s)
        idx[((size_t)n * PP + pb + t) * KK + s] = (int)(dl[s] & 0xFFFFFFFFu);
    }
  }
}

// ---------------- conv (MFMA bf16): y = A @ w^T + bias, fused per-WG BN partial stats ----------------
template<int KIN, bool GATHER, bool BNRELU>
__global__ __launch_bounds__(256) void conv_k(const u16* __restrict__ in,
                                              const int* __restrict__ idxp,
                                              const u16* __restrict__ wb,
                                              const float* __restrict__ bias,
                                              const float* __restrict__ st,
                                              u16* __restrict__ yout,
                                              float* __restrict__ partials) {
  constexpr int NKB = KIN / 32;
  __shared__ float sred[4][4][32];
  const int t = threadIdx.x;
  const int wv = t >> 6, l = t & 63, hi = l >> 4, lo = l & 15;
  const int rbase = blockIdx.x * 256 + wv * 64;

  bf16x8 wf[4][NKB];
  #pragma unroll
  for (int ob = 0; ob < 4; ++ob)
    #pragma unroll
    for (int kb = 0; kb < NKB; ++kb)
      wf[ob][kb] = *(const bf16x8*)(wb + (size_t)(ob*16 + lo) * KIN + kb*32 + hi*8);

  int qv[4];
  if constexpr (GATHER) {
    #pragma unroll
    for (int rb = 0; rb < 4; ++rb) {
      const int g = (rbase + rb*16) >> 4;     // one point per 16-row block
      qv[rb] = idxp[g * KK + lo];
    }
  }

  f32x4 acc[4][4];
  #pragma unroll
  for (int a = 0; a < 4; ++a)
    #pragma unroll
    for (int b = 0; b < 4; ++b) { f32x4 z = {0.f, 0.f, 0.f, 0.f}; acc[a][b] = z; }

  #pragma unroll
  for (int kb = 0; kb < NKB; ++kb) {
    float sv[8], tv[8];
    if constexpr (BNRELU) {
      const int k0 = kb*32 + hi*8;
      *(float4*)&sv[0] = *(const float4*)(st + k0);
      *(float4*)&sv[4] = *(const float4*)(st + k0 + 4);
      *(float4*)&tv[0] = *(const float4*)(st + KIN + k0);
      *(float4*)&tv[4] = *(const float4*)(st + KIN + k0 + 4);
    }
    bf16x8 af[4];
    #pragma unroll
    for (int rb = 0; rb < 4; ++rb) {
      if constexpr (GATHER) {
        const int g  = (rbase + rb*16) >> 4;
        const int k0 = kb*32 + hi*8;
        const bf16x8 fc = *(const bf16x8*)(in + (size_t)g * CC + (k0 & 63));
        if (kb < 2) {
          af[rb] = fc;                                   // h[:, :64] = fc (broadcast rows)
        } else {
          const int nn = g >> 11;
          const bf16x8 fv = *(const bf16x8*)(in + (size_t)(nn * PP + qv[rb]) * CC + (k0 & 63));
          bf16x8 df;
          #pragma unroll
          for (int j = 0; j < 8; ++j)
            df[j] = (short)f2b(b2f((u16)fc[j]) - b2f((u16)fv[j]));
          af[rb] = df;
        }
      } else {
        const int row = rbase + rb*16 + lo;
        const bf16x8 rv = *(const bf16x8*)(in + (size_t)row * KIN + kb*32 + hi*8);
        if constexpr (BNRELU) {
          bf16x8 tr;
          #pragma unroll
          for (int j = 0; j < 8; ++j) {
            const float x = fmaxf(b2f((u16)rv[j]) * sv[j] + tv[j], 0.f);
            tr[j] = (short)f2b(x);
          }
          af[rb] = tr;
        } else {
          af[rb] = rv;
        }
      }
    }
    #pragma unroll
    for (int ob = 0; ob < 4; ++ob)
      #pragma unroll
      for (int rb = 0; rb < 4; ++rb)
        acc[rb][ob] = __builtin_amdgcn_mfma_f32_16x16x32_bf16(wf[ob][kb], af[rb], acc[rb][ob], 0, 0, 0);
  }

  // epilogue: D[row=(l>>4)*4+reg -> out ch][col=l&15 -> A row]; store + per-channel sum/sumsq
  float ssum[16], qsum[16];
  #pragma unroll
  for (int j = 0; j < 16; ++j) { ssum[j] = 0.f; qsum[j] = 0.f; }
  #pragma unroll
  for (int ob = 0; ob < 4; ++ob) {
    const int o0 = ob*16 + hi*4;
    const float4 bv = *(const float4*)(bias + o0);
    #pragma unroll
    for (int rb = 0; rb < 4; ++rb) {
      const int row = rbase + rb*16 + lo;
      const float v0 = acc[rb][ob][0] + bv.x;
      const float v1 = acc[rb][ob][1] + bv.y;
      const float v2 = acc[rb][ob][2] + bv.z;
      const float v3 = acc[rb][ob][3] + bv.w;
      u16x4 pk; pk[0] = f2b(v0); pk[1] = f2b(v1); pk[2] = f2b(v2); pk[3] = f2b(v3);
      *(u16x4*)(yout + (size_t)row * CC + o0) = pk;
      ssum[ob*4+0] += v0; qsum[ob*4+0] += v0*v0;
      ssum[ob*4+1] += v1; qsum[ob*4+1] += v1*v1;
      ssum[ob*4+2] += v2; qsum[ob*4+2] += v2*v2;
      ssum[ob*4+3] += v3; qsum[ob*4+3] += v3*v3;
    }
  }
  #pragma unroll
  for (int m = 1; m < 16; m <<= 1) {
    #pragma unroll
    for (int j = 0; j < 16; ++j) {
      ssum[j] += __shfl_xor(ssum[j], m, 64);
      qsum[j] += __shfl_xor(qsum[j], m, 64);
    }
  }
  if (lo == 0) {
    #pragma unroll
    for (int j = 0; j < 16; ++j) {
      sred[wv][hi][j*2]   = ssum[j];
      sred[wv][hi][j*2+1] = qsum[j];
    }
  }
  __syncthreads();
  if (t < 128) {
    const int c = t & 63, half = t >> 6;
    const int slot = ((c >> 4) * 4 + (c & 3)) * 2 + half;   // ob*4+e
    const int h2 = (c >> 2) & 3;
    const float v = sred[0][h2][slot] + sred[1][h2][slot] + sred[2][h2][slot] + sred[3][h2][slot];
    partials[(size_t)blockIdx.x * 128 + half * 64 + c] = v;
  }
}

// ---------------- stage-1 reduce: nwg partial rows -> 64 rows ----------------
__global__ __launch_bounds__(256) void red1_k(const float* __restrict__ partials,
                                              float* __restrict__ out, int nwg) {
  __shared__ float accs[2][128];
  const int t = threadIdx.x, e = t & 127, h = t >> 7;
  float s = 0.f;
  for (int w = blockIdx.x + h * 64; w < nwg; w += 128)
    s += partials[(size_t)w * 128 + e];
  accs[h][e] = s;
  __syncthreads();
  if (t < 128) out[(size_t)blockIdx.x * 128 + t] = accs[0][t] + accs[1][t];
}

// ---------------- stage-2: 64 rows -> fused BN scale/bias ----------------
__global__ __launch_bounds__(128) void red2_k(const float* __restrict__ p2,
                                              const float* __restrict__ g,
                                              const float* __restrict__ be,
                                              float* __restrict__ st, float invM) {
  __shared__ float sq[128];
  const int t = threadIdx.x;            // element t: [0,64)=sum, [64,128)=sumsq
  float s = 0.f;
  #pragma unroll 8
  for (int w = 0; w < 64; ++w) s += p2[w * 128 + t];
  sq[t] = s;
  __syncthreads();
  if (t < 64) {
    const float S = sq[t], Q = sq[64 + t];
    const float m = S * invM;
    const float v = fmaxf(Q * invM - m * m, 0.f);
    const float sc = g[t] * rsqrtf(v + 1e-5f);
    st[t] = sc;
    st[64 + t] = be[t] - m * sc;
  }
}

// ---------------- final: bn2+relu, mean over K, + bn(shortcut), relu, (N,C,P) store ----------------
__global__ __launch_bounds__(256) void final_k(const u16* __restrict__ y2,
                                               const u16* __restrict__ ysc,
                                               const float* __restrict__ st2,
                                               const float* __restrict__ stS,
                                               float* __restrict__ out) {
  __shared__ float ot[64][68];
  const int b = blockIdx.x, t = threadIdx.x;
  const int n = b >> 5, p0 = (b & 31) * 64;
  const int phh = t >> 2, jh = t & 3, c0 = jh * 16;
  const int g = n * PP + p0 + phh;
  float acc[16];
  #pragma unroll
  for (int i = 0; i < 16; ++i) acc[i] = 0.f;
  float sv[16], tv[16];
  #pragma unroll
  for (int i = 0; i < 16; ++i) { sv[i] = st2[c0 + i]; tv[i] = st2[64 + c0 + i]; }
  for (int k = 0; k < KK; ++k) {
    const u16* rp = y2 + ((size_t)g * KK + k) * CC + c0;
    const bf16x8 v0 = *(const bf16x8*)rp;
    const bf16x8 v1 = *(const bf16x8*)(rp + 8);
    #pragma unroll
    for (int j = 0; j < 8; ++j) {
      acc[j]     += fmaxf(b2f((u16)v0[j]) * sv[j]     + tv[j],     0.f);
      acc[8 + j] += fmaxf(b2f((u16)v1[j]) * sv[8 + j] + tv[8 + j], 0.f);
    }
  }
  const u16* sp = ysc + (size_t)g * CC + c0;
  const bf16x8 s0 = *(const bf16x8*)sp;
  const bf16x8 s1 = *(const bf16x8*)(sp + 8);
  #pragma unroll
  for (int i = 0; i < 16; ++i) {
    const float scx = b2f((u16)(i < 8 ? s0[i] : s1[i - 8])) * stS[c0 + i] + stS[64 + c0 + i];
    ot[c0 + i][phh] = fmaxf(acc[i] * (1.f / 16.f) + scx, 0.f);
  }
  __syncthreads();
  const int c = t >> 2, pc = t & 3;
  const float* src = &ot[c][pc * 16];
  float* dst = out + (size_t)n * CC * PP + (size_t)c * PP + p0 + pc * 16;
  #pragma unroll
  for (int j = 0; j < 16; j += 4) *(float4*)(dst + j) = *(const float4*)(src + j);
}

// ---------------- host ----------------
extern "C" void kernel_launch(void* const* d_in, const int* in_sizes, int n_in,
                              void* d_out, int out_size, void* d_ws, size_t ws_size,
                              hipStream_t stream) {
  (void)in_sizes; (void)n_in; (void)out_size; (void)ws_size;
  const float* F   = (const float*)d_in[0];
  const float* w0  = (const float*)d_in[1];
  const float* b0  = (const float*)d_in[2];
  const float* g0  = (const float*)d_in[3];
  const float* be0 = (const float*)d_in[4];
  const float* w1  = (const float*)d_in[5];
  const float* b1  = (const float*)d_in[6];
  const float* g1  = (const float*)d_in[7];
  const float* be1 = (const float*)d_in[8];
  const float* w2  = (const float*)d_in[9];
  const float* b2  = (const float*)d_in[10];
  const float* g2  = (const float*)d_in[11];
  const float* be2 = (const float*)d_in[12];
  const float* wS  = (const float*)d_in[13];
  const float* bS  = (const float*)d_in[14];
  const float* gS  = (const float*)d_in[15];
  const float* beS = (const float*)d_in[16];

  char* ws = (char*)d_ws;
  size_t off = 0;
  auto carve = [&](size_t bytes) -> void* {
    void* p = ws + off;
    off += (bytes + 255) & ~(size_t)255;
    return p;
  };
  float* X        = (float*)carve((size_t)NPTS * CC * 4);       // 8.4 MB
  u16*   Xb       = (u16*)  carve((size_t)NPTS * CC * 2);       // 4.2 MB
  float* rr       = (float*)carve((size_t)NPTS * 4);            // 128 KB
  int*   idx      = (int*)  carve((size_t)NPTS * KK * 4);       // 2 MB
  u16*   wb0      = (u16*)  carve(8192 * 2);
  u16*   wb1      = (u16*)  carve(4096 * 2);
  u16*   wb2      = (u16*)  carve(4096 * 2);
  u16*   wbs      = (u16*)  carve(4096 * 2);
  u16*   y        = (u16*)  carve((size_t)MROWS * CC * 2);      // 67 MB
  u16*   ysc      = (u16*)  carve((size_t)NPTS * CC * 2);       // 4.2 MB
  float* partials = (float*)carve((size_t)2048 * 128 * 4);      // 1 MB
  float* p2       = (float*)carve((size_t)64 * 128 * 4);        // 32 KB
  float* st0      = (float*)carve(128 * 4);
  float* st1      = (float*)carve(128 * 4);
  float* st2      = (float*)carve(128 * 4);
  float* stS      = (float*)carve(128 * 4);

  prep_k<<<NPTS / 256, 256, 0, stream>>>(F, X, Xb, rr);
  cvtw_k<<<80, 256, 0, stream>>>(w0, w1, w2, wS, wb0, wb1, wb2, wbs);
  knn_k<<<NB * (PP / 64), 512, 0, stream>>>(X, rr, idx);

  conv_k<128, true,  false><<<MROWS / 256, 256, 0, stream>>>(Xb, idx, wb0, b0, nullptr, y, partials);
  red1_k<<<64, 256, 0, stream>>>(partials, p2, MROWS / 256);
  red2_k<<<1, 128, 0, stream>>>(p2, g0, be0, st0, 1.f / (float)MROWS);

  conv_k<64, false, true><<<MROWS / 256, 256, 0, stream>>>(y, nullptr, wb1, b1, st0, y, partials);
  red1_k<<<64, 256, 0, stream>>>(partials, p2, MROWS / 256);
  red2_k<<<1, 128, 0, stream>>>(p2, g1, be1, st1, 1.f / (float)MROWS);

  conv_k<64, false, true><<<MROWS / 256, 256, 0, stream>>>(y, nullptr, wb2, b2, st1, y, partials);
  red1_k<<<64, 256, 0, stream>>>(partials, p2, MROWS / 256);
  red2_k<<<1, 128, 0, stream>>>(p2, g2, be2, st2, 1.f / (float)MROWS);

  conv_k<64, false, false><<<NPTS / 256, 256, 0, stream>>>(Xb, nullptr, wbs, bS, nullptr, ysc, partials);
  red1_k<<<64, 256, 0, stream>>>(partials, p2, NPTS / 256);
  red2_k<<<1, 128, 0, stream>>>(p2, gS, beS, stS, 1.f / (float)NPTS);

  final_k<<<NB * (PP / 64), 256, 0, stream>>>(y, ysc, st2, stS, (float*)d_out);
}

// Round 6
// 418.965 us; speedup vs baseline: 2.4111x; 1.0055x over previous
//
#include <hip/hip_runtime.h>

using u16    = unsigned short;
using u64    = unsigned long long;
using bf16x8 = __attribute__((ext_vector_type(8))) short;
using f32x4  = __attribute__((ext_vector_type(4))) float;
using u16x4  = __attribute__((ext_vector_type(4))) u16;

#define NB   16
#define PP   2048
#define CC   64
#define KK   16
#define MROWS (NB*PP*KK)   /* 524288 */
#define NPTS  (NB*PP)      /* 32768  */

__device__ __forceinline__ float b2f(u16 u) { return __uint_as_float(((unsigned)u) << 16); }
__device__ __forceinline__ u16 f2b(float f) {
  unsigned u = __float_as_uint(f);
  return (u16)((u + 0x7fffu + ((u >> 16) & 1u)) >> 16);
}

// order-preserving (d, qi) -> u64 key: smaller key == smaller d, tie -> smaller qi
__device__ __forceinline__ u64 dkey(float d, int qi) {
  unsigned u = __float_as_uint(d);
  u = u ^ (((unsigned)((int)u >> 31)) | 0x80000000u);
  return ((u64)u << 32) | (unsigned)qi;
}

template<bool UP>
__device__ __forceinline__ void ce(u64 &a, u64 &b) {
  const bool lt = a < b;
  const u64 lo = lt ? a : b;
  const u64 hi = lt ? b : a;
  if (UP) { a = lo; b = hi; } else { a = hi; b = lo; }
}

// full bitonic sort, ascending
__device__ __forceinline__ void sort16(u64 (&v)[16]) {
  #pragma unroll
  for (int k = 2; k <= 16; k <<= 1) {
    #pragma unroll
    for (int j = k >> 1; j > 0; j >>= 1) {
      #pragma unroll
      for (int i = 0; i < 16; ++i) {
        const int l = i ^ j;
        if (l > i) {
          if ((i & k) == 0) ce<true>(v[i], v[l]);
          else              ce<false>(v[i], v[l]);
        }
      }
    }
  }
}

// dl (sorted asc) <- lowest 16 of union(dl, nb), nb sorted asc; result sorted asc
__device__ __forceinline__ void merge16(u64 (&dl)[16], const u64 (&nb)[16]) {
  u64 t[16];
  #pragma unroll
  for (int s = 0; s < 16; ++s) {
    const u64 a = dl[s], b = nb[15 - s];
    t[s] = a < b ? a : b;                 // bitonic sequence of the 16 smallest
  }
  #pragma unroll
  for (int j = 8; j > 0; j >>= 1) {
    #pragma unroll
    for (int i = 0; i < 16; ++i) {
      const int l = i ^ j;
      if (l > i) ce<true>(t[i], t[l]);
    }
  }
  #pragma unroll
  for (int s = 0; s < 16; ++s) dl[s] = t[s];
}

// ---------------- prep: features (N,C,P) -> X (N,P,C) fp32 + bf16, r = sum x^2 ----------------
__global__ __launch_bounds__(256) void prep_k(const float* __restrict__ F,
                                              float* __restrict__ X,
                                              u16* __restrict__ Xb,
                                              float* __restrict__ r) {
  int gidx = blockIdx.x * 256 + threadIdx.x;      // 0..32767
  int n = gidx >> 11, p = gidx & 2047;
  const float* src = F + (size_t)n * CC * PP + p;
  float v[CC];
  float rr = 0.f;
  #pragma unroll
  for (int c = 0; c < CC; ++c) { v[c] = src[(size_t)c * PP]; rr += v[c] * v[c]; }
  float* dst = X + (size_t)gidx * CC;
  #pragma unroll
  for (int c = 0; c < CC; c += 4) {
    float4 w; w.x = v[c]; w.y = v[c+1]; w.z = v[c+2]; w.w = v[c+3];
    *(float4*)(dst + c) = w;
  }
  u16* db = Xb + (size_t)gidx * CC;
  #pragma unroll
  for (int c = 0; c < CC; c += 8) {
    bf16x8 w8;
    #pragma unroll
    for (int j = 0; j < 8; ++j) w8[j] = (short)f2b(v[c + j]);
    *(bf16x8*)(db + c) = w8;
  }
  r[gidx] = rr;
}

// ---------------- weight fp32 -> bf16 ----------------
__global__ __launch_bounds__(256) void cvtw_k(const float* __restrict__ w0, const float* __restrict__ w1,
                                              const float* __restrict__ w2, const float* __restrict__ wsb,
                                              u16* __restrict__ b0, u16* __restrict__ b1,
                                              u16* __restrict__ b2, u16* __restrict__ bs) {
  int i = blockIdx.x * 256 + threadIdx.x;         // 20480 total
  if (i < 8192)        b0[i]          = f2b(w0[i]);
  else if (i < 12288)  b1[i - 8192]   = f2b(w1[i - 8192]);
  else if (i < 16384)  b2[i - 12288]  = f2b(w2[i - 12288]);
  else if (i < 20480)  bs[i - 16384]  = f2b(wsb[i - 16384]);
}

// ---------------- fused KNN v5.1: WG=512 pinned at 4 waves/EU, conflict-free staging ----------------
// WG owns 64 p-rows x all 2048 q.  Per 128-q tile:
//   GEMM: pg = t>>5 (4 rows pg*4..+3), qh = t&31 (4 cols qh*4..+3) -> acc[4][4]
//         per-(p,q) FMA chain over c ascending == prior rounds -> bitwise-identical distances
//   D-tile overlays Xq LDS (dead after GEMM), XOR-swizzled 16B blocks
//   select: row t&63, eighth t>>6 (== wave): one 16-candidate batch -> sort16 + merge16
__global__ __launch_bounds__(512, 4) __attribute__((amdgpu_waves_per_eu(4, 4)))
void knn_k(const float* __restrict__ X,
           const float* __restrict__ r,
           int* __restrict__ idx) {
  __shared__ float lds[12800];          // Xp [64][68] @ 0 ; Xq/D [64][132] @ 4352  (51.2 KB)
  float* Xp = lds;
  float* Xq = lds + 4352;

  const int n  = blockIdx.x >> 5;
  const int pb = (blockIdx.x & 31) * 64;
  const int t  = threadIdx.x;
  const float* Xn = X + (size_t)n * PP * CC;
  const float* rb = r + (size_t)n * PP;

  const int qh   = t & 31;              // GEMM: 4 q-cols qh*4..+3
  const int pg   = t >> 5;              // GEMM: 4 p-rows pg*4..+3 (0..15)
  const int prow = t & 63;              // select: own row
  const int w8   = t >> 6;              // select: eighth (== wave index)
  const int u4   = (prow & 7) * 4;      // select-side swizzle key

  { // stage Xp transposed [c][p]: wave-uniform channel group, pr consecutive -> conflict-free
    const int pr = t & 63, ct = t >> 6;
    const float* src = Xn + (size_t)(pb + pr) * CC + ct * 8;
    #pragma unroll
    for (int j = 0; j < 8; j += 4) {
      float4 v = *(const float4*)(src + j);
      Xp[(ct*8 + j + 0) * 68 + pr] = v.x;
      Xp[(ct*8 + j + 1) * 68 + pr] = v.y;
      Xp[(ct*8 + j + 2) * 68 + pr] = v.z;
      Xp[(ct*8 + j + 3) * 68 + pr] = v.w;
    }
  }

  u64 dl[16];
  #pragma unroll
  for (int s = 0; s < 16; ++s) dl[s] = ~0ULL;

  #pragma unroll 1
  for (int qb = 0; qb < PP; qb += 128) {
    __syncthreads();                    // previous select readers done (also covers Xp stage)
    { // stage Xq transposed [c][q]: hs = t>>7 owns 16 channels; qr = t&127 consecutive
      const int qr = t & 127, hs = t >> 7;
      const float* src = Xn + (size_t)(qb + qr) * CC + hs * 16;
      #pragma unroll
      for (int j = 0; j < 16; j += 4) {
        float4 v = *(const float4*)(src + j);
        Xq[(hs*16 + j + 0) * 132 + qr] = v.x;
        Xq[(hs*16 + j + 1) * 132 + qr] = v.y;
        Xq[(hs*16 + j + 2) * 132 + qr] = v.z;
        Xq[(hs*16 + j + 3) * 132 + qr] = v.w;
      }
    }
    __syncthreads();

    float acc[4][4];
    #pragma unroll
    for (int i = 0; i < 4; ++i)
      #pragma unroll
      for (int j = 0; j < 4; ++j) acc[i][j] = 0.f;

    #pragma unroll 4
    for (int c = 0; c < 64; ++c) {
      const float4 a = *(const float4*)&Xp[c*68 + pg*4];
      const float4 bq = *(const float4*)&Xq[c*132 + qh*4];
      float av[4] = {a.x, a.y, a.z, a.w};
      float bv[4] = {bq.x, bq.y, bq.z, bq.w};
      #pragma unroll
      for (int i = 0; i < 4; ++i)
        #pragma unroll
        for (int j = 0; j < 4; ++j)
          acc[i][j] = fmaf(av[i], bv[j], acc[i][j]);
    }
    __syncthreads();                    // all Xq reads done -> safe to overlay D

    { // write D tile (d = rq - 2*dot, self -> +big), block qh stored at slot qh^((p&7)*4)
      const int qg0 = qb + qh*4;
      const float4 rv = *(const float4*)(rb + qg0);
      #pragma unroll
      for (int i = 0; i < 4; ++i) {
        const int p  = pg*4 + i;
        const int pgl = pb + p;
        float d0 = rv.x - 2.f * acc[i][0]; if (qg0 + 0 == pgl) d0 = 3.0e38f;
        float d1 = rv.y - 2.f * acc[i][1]; if (qg0 + 1 == pgl) d1 = 3.0e38f;
        float d2 = rv.z - 2.f * acc[i][2]; if (qg0 + 2 == pgl) d2 = 3.0e38f;
        float d3 = rv.w - 2.f * acc[i][3]; if (qg0 + 3 == pgl) d3 = 3.0e38f;
        float4 dv; dv.x = d0; dv.y = d1; dv.z = d2; dv.w = d3;
        *(float4*)&Xq[(size_t)p * 132 + ((qh ^ ((p & 7) * 4)) * 4)] = dv;
      }
    }
    __syncthreads();

    // select: thread scans row `prow`, blocks b = w8*4..+3 -> one 16-candidate batch
    {
      u64 nb[16];
      const float* drow = &Xq[(size_t)prow * 132];
      const int bbase = (w8 * 4) ^ u4;        // low 2 bits of both are 0 -> (b^u4) = bbase + bb
      #pragma unroll
      for (int bb = 0; bb < 4; ++bb) {
        const float4 dv = *(const float4*)(drow + (bbase + bb) * 4);
        const int qg = qb + (w8*4 + bb) * 4;
        nb[bb*4+0] = dkey(dv.x, qg+0);
        nb[bb*4+1] = dkey(dv.y, qg+1);
        nb[bb*4+2] = dkey(dv.z, qg+2);
        nb[bb*4+3] = dkey(dv.w, qg+3);
      }
      sort16(nb);
      merge16(dl, nb);
    }
  }

  // merge 8 partial sorted lists per row: pair-merge (t vs t+256), then 4-way via LDS
  __syncthreads();
  {
    u64* mb = (u64*)lds;                // 16*256 u64 = 32 KB
    if (t >= 256) {
      #pragma unroll
      for (int s = 0; s < 16; ++s) mb[s * 256 + (t - 256)] = dl[s];
    }
    __syncthreads();
    if (t < 256) {
      u64 nb[16];
      #pragma unroll
      for (int s = 0; s < 16; ++s) nb[s] = mb[s * 256 + t];
      merge16(dl, nb);
    }
    __syncthreads();
    if (t < 256) {
      #pragma unroll
      for (int s = 0; s < 16; ++s) mb[s * 256 + t] = dl[s];
    }
    __syncthreads();
    if (t < 64) {
      #pragma unroll 1
      for (int j = 1; j < 4; ++j) {
        u64 nb[16];
        #pragma unroll
        for (int s = 0; s < 16; ++s) nb[s] = mb[s * 256 + (t + 64 * j)];
        merge16(dl, nb);
      }
      #pragma unroll
      for (int s = 0; s < 16; ++s)
        idx[((size_t)n * PP + pb + t) * KK + s] = (int)(dl[s] & 0xFFFFFFFFu);
    }
  }
}

// ---------------- conv (MFMA bf16): y = A @ w^T + bias, fused per-WG BN partial stats ----------------
template<int KIN, bool GATHER, bool BNRELU>
__global__ __launch_bounds__(256) void conv_k(const u16* __restrict__ in,
                                              const int* __restrict__ idxp,
                                              const u16* __restrict__ wb,
                                              const float* __restrict__ bias,
                                              const float* __restrict__ st,
                                              u16* __restrict__ yout,
                                              float* __restrict__ partials) {
  constexpr int NKB = KIN / 32;
  __shared__ float sred[4][4][32];
  const int t = threadIdx.x;
  const int wv = t >> 6, l = t & 63, hi = l >> 4, lo = l & 15;
  const int rbase = blockIdx.x * 256 + wv * 64;

  bf16x8 wf[4][NKB];
  #pragma unroll
  for (int ob = 0; ob < 4; ++ob)
    #pragma unroll
    for (int kb = 0; kb < NKB; ++kb)
      wf[ob][kb] = *(const bf16x8*)(wb + (size_t)(ob*16 + lo) * KIN + kb*32 + hi*8);

  int qv[4];
  if constexpr (GATHER) {
    #pragma unroll
    for (int rb = 0; rb < 4; ++rb) {
      const int g = (rbase + rb*16) >> 4;     // one point per 16-row block
      qv[rb] = idxp[g * KK + lo];
    }
  }

  f32x4 acc[4][4];
  #pragma unroll
  for (int a = 0; a < 4; ++a)
    #pragma unroll
    for (int b = 0; b < 4; ++b) { f32x4 z = {0.f, 0.f, 0.f, 0.f}; acc[a][b] = z; }

  #pragma unroll
  for (int kb = 0; kb < NKB; ++kb) {
    float sv[8], tv[8];
    if constexpr (BNRELU) {
      const int k0 = kb*32 + hi*8;
      *(float4*)&sv[0] = *(const float4*)(st + k0);
      *(float4*)&sv[4] = *(const float4*)(st + k0 + 4);
      *(float4*)&tv[0] = *(const float4*)(st + KIN + k0);
      *(float4*)&tv[4] = *(const float4*)(st + KIN + k0 + 4);
    }
    bf16x8 af[4];
    #pragma unroll
    for (int rb = 0; rb < 4; ++rb) {
      if constexpr (GATHER) {
        const int g  = (rbase + rb*16) >> 4;
        const int k0 = kb*32 + hi*8;
        const bf16x8 fc = *(const bf16x8*)(in + (size_t)g * CC + (k0 & 63));
        if (kb < 2) {
          af[rb] = fc;                                   // h[:, :64] = fc (broadcast rows)
        } else {
          const int nn = g >> 11;
          const bf16x8 fv = *(const bf16x8*)(in + (size_t)(nn * PP + qv[rb]) * CC + (k0 & 63));
          bf16x8 df;
          #pragma unroll
          for (int j = 0; j < 8; ++j)
            df[j] = (short)f2b(b2f((u16)fc[j]) - b2f((u16)fv[j]));
          af[rb] = df;
        }
      } else {
        const int row = rbase + rb*16 + lo;
        const bf16x8 rv = *(const bf16x8*)(in + (size_t)row * KIN + kb*32 + hi*8);
        if constexpr (BNRELU) {
          bf16x8 tr;
          #pragma unroll
          for (int j = 0; j < 8; ++j) {
            const float x = fmaxf(b2f((u16)rv[j]) * sv[j] + tv[j], 0.f);
            tr[j] = (short)f2b(x);
          }
          af[rb] = tr;
        } else {
          af[rb] = rv;
        }
      }
    }
    #pragma unroll
    for (int ob = 0; ob < 4; ++ob)
      #pragma unroll
      for (int rb = 0; rb < 4; ++rb)
        acc[rb][ob] = __builtin_amdgcn_mfma_f32_16x16x32_bf16(wf[ob][kb], af[rb], acc[rb][ob], 0, 0, 0);
  }

  // epilogue: D[row=(l>>4)*4+reg -> out ch][col=l&15 -> A row]; store + per-channel sum/sumsq
  float ssum[16], qsum[16];
  #pragma unroll
  for (int j = 0; j < 16; ++j) { ssum[j] = 0.f; qsum[j] = 0.f; }
  #pragma unroll
  for (int ob = 0; ob < 4; ++ob) {
    const int o0 = ob*16 + hi*4;
    const float4 bv = *(const float4*)(bias + o0);
    #pragma unroll
    for (int rb = 0; rb < 4; ++rb) {
      const int row = rbase + rb*16 + lo;
      const float v0 = acc[rb][ob][0] + bv.x;
      const float v1 = acc[rb][ob][1] + bv.y;
      const float v2 = acc[rb][ob][2] + bv.z;
      const float v3 = acc[rb][ob][3] + bv.w;
      u16x4 pk; pk[0] = f2b(v0); pk[1] = f2b(v1); pk[2] = f2b(v2); pk[3] = f2b(v3);
      *(u16x4*)(yout + (size_t)row * CC + o0) = pk;
      ssum[ob*4+0] += v0; qsum[ob*4+0] += v0*v0;
      ssum[ob*4+1] += v1; qsum[ob*4+1] += v1*v1;
      ssum[ob*4+2] += v2; qsum[ob*4+2] += v2*v2;
      ssum[ob*4+3] += v3; qsum[ob*4+3] += v3*v3;
    }
  }
  #pragma unroll
  for (int m = 1; m < 16; m <<= 1) {
    #pragma unroll
    for (int j = 0; j < 16; ++j) {
      ssum[j] += __shfl_xor(ssum[j], m, 64);
      qsum[j] += __shfl_xor(qsum[j], m, 64);
    }
  }
  if (lo == 0) {
    #pragma unroll
    for (int j = 0; j < 16; ++j) {
      sred[wv][hi][j*2]   = ssum[j];
      sred[wv][hi][j*2+1] = qsum[j];
    }
  }
  __syncthreads();
  if (t < 128) {
    const int c = t & 63, half = t >> 6;
    const int slot = ((c >> 4) * 4 + (c & 3)) * 2 + half;   // ob*4+e
    const int h2 = (c >> 2) & 3;
    const float v = sred[0][h2][slot] + sred[1][h2][slot] + sred[2][h2][slot] + sred[3][h2][slot];
    partials[(size_t)blockIdx.x * 128 + half * 64 + c] = v;
  }
}

// ---------------- stage-1 reduce: nwg partial rows -> 64 rows ----------------
__global__ __launch_bounds__(256) void red1_k(const float* __restrict__ partials,
                                              float* __restrict__ out, int nwg) {
  __shared__ float accs[2][128];
  const int t = threadIdx.x, e = t & 127, h = t >> 7;
  float s = 0.f;
  for (int w = blockIdx.x + h * 64; w < nwg; w += 128)
    s += partials[(size_t)w * 128 + e];
  accs[h][e] = s;
  __syncthreads();
  if (t < 128) out[(size_t)blockIdx.x * 128 + t] = accs[0][t] + accs[1][t];
}

// ---------------- stage-2: 64 rows -> fused BN scale/bias ----------------
__global__ __launch_bounds__(128) void red2_k(const float* __restrict__ p2,
                                              const float* __restrict__ g,
                                              const float* __restrict__ be,
                                              float* __restrict__ st, float invM) {
  __shared__ float sq[128];
  const int t = threadIdx.x;            // element t: [0,64)=sum, [64,128)=sumsq
  float s = 0.f;
  #pragma unroll 8
  for (int w = 0; w < 64; ++w) s += p2[w * 128 + t];
  sq[t] = s;
  __syncthreads();
  if (t < 64) {
    const float S = sq[t], Q = sq[64 + t];
    const float m = S * invM;
    const float v = fmaxf(Q * invM - m * m, 0.f);
    const float sc = g[t] * rsqrtf(v + 1e-5f);
    st[t] = sc;
    st[64 + t] = be[t] - m * sc;
  }
}

// ---------------- final: bn2+relu, mean over K, + bn(shortcut), relu, (N,C,P) store ----------------
__global__ __launch_bounds__(256) void final_k(const u16* __restrict__ y2,
                                               const u16* __restrict__ ysc,
                                               const float* __restrict__ st2,
                                               const float* __restrict__ stS,
                                               float* __restrict__ out) {
  __shared__ float ot[64][68];
  const int b = blockIdx.x, t = threadIdx.x;
  const int n = b >> 5, p0 = (b & 31) * 64;
  const int phh = t >> 2, jh = t & 3, c0 = jh * 16;
  const int g = n * PP + p0 + phh;
  float acc[16];
  #pragma unroll
  for (int i = 0; i < 16; ++i) acc[i] = 0.f;
  float sv[16], tv[16];
  #pragma unroll
  for (int i = 0; i < 16; ++i) { sv[i] = st2[c0 + i]; tv[i] = st2[64 + c0 + i]; }
  for (int k = 0; k < KK; ++k) {
    const u16* rp = y2 + ((size_t)g * KK + k) * CC + c0;
    const bf16x8 v0 = *(const bf16x8*)rp;
    const bf16x8 v1 = *(const bf16x8*)(rp + 8);
    #pragma unroll
    for (int j = 0; j < 8; ++j) {
      acc[j]     += fmaxf(b2f((u16)v0[j]) * sv[j]     + tv[j],     0.f);
      acc[8 + j] += fmaxf(b2f((u16)v1[j]) * sv[8 + j] + tv[8 + j], 0.f);
    }
  }
  const u16* sp = ysc + (size_t)g * CC + c0;
  const bf16x8 s0 = *(const bf16x8*)sp;
  const bf16x8 s1 = *(const bf16x8*)(sp + 8);
  #pragma unroll
  for (int i = 0; i < 16; ++i) {
    const float scx = b2f((u16)(i < 8 ? s0[i] : s1[i - 8])) * stS[c0 + i] + stS[64 + c0 + i];
    ot[c0 + i][phh] = fmaxf(acc[i] * (1.f / 16.f) + scx, 0.f);
  }
  __syncthreads();
  const int c = t >> 2, pc = t & 3;
  const float* src = &ot[c][pc * 16];
  float* dst = out + (size_t)n * CC * PP + (size_t)c * PP + p0 + pc * 16;
  #pragma unroll
  for (int j = 0; j < 16; j += 4) *(float4*)(dst + j) = *(const float4*)(src + j);
}

// ---------------- host ----------------
extern "C" void kernel_launch(void* const* d_in, const int* in_sizes, int n_in,
                              void* d_out, int out_size, void* d_ws, size_t ws_size,
                              hipStream_t stream) {
  (void)in_sizes; (void)n_in; (void)out_size; (void)ws_size;
  const float* F   = (const float*)d_in[0];
  const float* w0  = (const float*)d_in[1];
  const float* b0  = (const float*)d_in[2];
  const float* g0  = (const float*)d_in[3];
  const float* be0 = (const float*)d_in[4];
  const float* w1  = (const float*)d_in[5];
  const float* b1  = (const float*)d_in[6];
  const float* g1  = (const float*)d_in[7];
  const float* be1 = (const float*)d_in[8];
  const float* w2  = (const float*)d_in[9];
  const float* b2  = (const float*)d_in[10];
  const float* g2  = (const float*)d_in[11];
  const float* be2 = (const float*)d_in[12];
  const float* wS  = (const float*)d_in[13];
  const float* bS  = (const float*)d_in[14];
  const float* gS  = (const float*)d_in[15];
  const float* beS = (const float*)d_in[16];

  char* ws = (char*)d_ws;
  size_t off = 0;
  auto carve = [&](size_t bytes) -> void* {
    void* p = ws + off;
    off += (bytes + 255) & ~(size_t)255;
    return p;
  };
  float* X        = (float*)carve((size_t)NPTS * CC * 4);       // 8.4 MB
  u16*   Xb       = (u16*)  carve((size_t)NPTS * CC * 2);       // 4.2 MB
  float* rr       = (float*)carve((size_t)NPTS * 4);            // 128 KB
  int*   idx      = (int*)  carve((size_t)NPTS * KK * 4);       // 2 MB
  u16*   wb0      = (u16*)  carve(8192 * 2);
  u16*   wb1      = (u16*)  carve(4096 * 2);
  u16*   wb2      = (u16*)  carve(4096 * 2);
  u16*   wbs      = (u16*)  carve(4096 * 2);
  u16*   y        = (u16*)  carve((size_t)MROWS * CC * 2);      // 67 MB
  u16*   ysc      = (u16*)  carve((size_t)NPTS * CC * 2);       // 4.2 MB
  float* partials = (float*)carve((size_t)2048 * 128 * 4);      // 1 MB
  float* p2       = (float*)carve((size_t)64 * 128 * 4);        // 32 KB
  float* st0      = (float*)carve(128 * 4);
  float* st1      = (float*)carve(128 * 4);
  float* st2      = (float*)carve(128 * 4);
  float* stS      = (float*)carve(128 * 4);

  prep_k<<<NPTS / 256, 256, 0, stream>>>(F, X, Xb, rr);
  cvtw_k<<<80, 256, 0, stream>>>(w0, w1, w2, wS, wb0, wb1, wb2, wbs);
  knn_k<<<NB * (PP / 64), 512, 0, stream>>>(X, rr, idx);

  conv_k<128, true,  false><<<MROWS / 256, 256, 0, stream>>>(Xb, idx, wb0, b0, nullptr, y, partials);
  red1_k<<<64, 256, 0, stream>>>(partials, p2, MROWS / 256);
  red2_k<<<1, 128, 0, stream>>>(p2, g0, be0, st0, 1.f / (float)MROWS);

  conv_k<64, false, true><<<MROWS / 256, 256, 0, stream>>>(y, nullptr, wb1, b1, st0, y, partials);
  red1_k<<<64, 256, 0, stream>>>(partials, p2, MROWS / 256);
  red2_k<<<1, 128, 0, stream>>>(p2, g1, be1, st1, 1.f / (float)MROWS);

  conv_k<64, false, true><<<MROWS / 256, 256, 0, stream>>>(y, nullptr, wb2, b2, st1, y, partials);
  red1_k<<<64, 256, 0, stream>>>(partials, p2, MROWS / 256);
  red2_k<<<1, 128, 0, stream>>>(p2, g2, be2, st2, 1.f / (float)MROWS);

  conv_k<64, false, false><<<NPTS / 256, 256, 0, stream>>>(Xb, nullptr, wbs, bS, nullptr, ysc, partials);
  red1_k<<<64, 256, 0, stream>>>(partials, p2, NPTS / 256);
  red2_k<<<1, 128, 0, stream>>>(p2, gS, beS, stS, 1.f / (float)NPTS);

  final_k<<<NB * (PP / 64), 256, 0, stream>>>(y, ysc, st2, stS, (float*)d_out);
}